// Round 3
// baseline (7961.124 us; speedup 1.0000x reference)
//
#include <hip/hip_runtime.h>
#include <hip/hip_bf16.h>
#include <math.h>

// ============================================================================
// GSTRGCT: full forward.
// N=512 B=32 T_IN=24 T_OUT=12 C_IN=1 C_OUT=64 D=64 H=8 K=3 LAYERS=2 DFF=256
// MA_KERNEL=25, top_k = int(log(24)) = 3. Output dtype: FLOAT32.
// ============================================================================

// ---------------- workspace layout (in floats) ----------------
static const size_t OFF_W   = 0;                       // 512*512 (logits -> softmax W)
static const size_t OFF_SA  = OFF_W  + 512*512;        // eigen squaring ping
static const size_t OFF_SB  = OFF_SA + 512*512;        // eigen squaring pong
static const size_t OFF_WX  = OFF_SB + 512*512;        // 768*512  w_x
static const size_t OFF_Y1  = OFF_WX + 768*512;        // x @ C1
static const size_t OFF_Y2  = OFF_Y1 + 768*512;        // x @ C2
static const size_t OFF_Z1  = OFF_Y2 + 768*512;        // wx @ C1
static const size_t OFF_Z2  = OFF_Z1 + 768*512;        // wx @ C2
static const size_t OFF_TR  = OFF_Z2 + 768*512;        // 16384*12 t_relu
static const size_t OFF_PE  = OFF_TR + 16384*12;       // 24*64 positional enc
static const size_t OFF_CS1 = OFF_PE + 24*64;          // 512 colsum of C1
static const size_t OFF_CS2 = OFF_CS1 + 512;           // 512 colsum of C2
static const size_t OFF_V0  = OFF_CS2 + 512;           // power-iter vec ping
static const size_t OFF_V1  = OFF_V0 + 512;            // power-iter vec pong
static const size_t OFF_NA  = OFF_V1 + 512;            // normAcc[32] (padded 64)
static const size_t OFF_SC  = OFF_NA + 64;             // scalars: [0]=G [1]=inv_m [2]=lam [3]=a [4]=c ; [8]=m_bits(uint)

#define EIG_H 0.125f
#define EIG_K 14        /* squarings: t = h*2^k = 2048 */
#define MV_STEPS 32

// ---------------------------------------------------------------------------
// prep: PE table, power-iter seed vector, normAcc zero
// ---------------------------------------------------------------------------
__global__ __launch_bounds__(256) void k_prep(float* __restrict__ wsf) {
  const int t = threadIdx.x;
  for (int idx = t; idx < 24 * 64; idx += 256) {
    int l = idx >> 6, d = idx & 63;
    int i = d >> 1;
    float div = expf((float)(2 * i) * (-9.210340371976184f / 64.0f)); // -ln(1e4)/64
    float ang = (float)l * div;
    wsf[OFF_PE + idx] = (d & 1) ? cosf(ang) : sinf(ang);
  }
  for (int idx = t; idx < 512; idx += 256)
    wsf[OFF_V0 + idx] = sinf((float)idx * 12.9898f + 0.5f) + 0.01f;
  for (int idx = t; idx < 64; idx += 256)
    wsf[OFF_NA + idx] = 0.0f;
}

// ---------------------------------------------------------------------------
// logits = s_w @ swnn_w^T + swnn_b   (NT gemm, 512x512x512)
// ---------------------------------------------------------------------------
__global__ __launch_bounds__(256) void k_gemm_logits(
    const float* __restrict__ A, const float* __restrict__ Bm,
    const float* __restrict__ bias, float* __restrict__ C) {
  __shared__ float As[32][33], Bs[32][33];
  const int tx = threadIdx.x & 31, ty = threadIdx.x >> 5;
  const int rb = blockIdx.y * 32, cb = blockIdx.x * 32;
  float acc[4] = {0.f, 0.f, 0.f, 0.f};
  for (int kk = 0; kk < 512; kk += 32) {
    for (int idx = threadIdx.x; idx < 1024; idx += 256) {
      int r = idx >> 5, c = idx & 31;
      As[r][c] = A[(rb + r) * 512 + kk + c];
      Bs[c][r] = Bm[(cb + r) * 512 + kk + c];   // Bs[k][j]
    }
    __syncthreads();
    for (int k2 = 0; k2 < 32; ++k2) {
      float bv = Bs[k2][tx];
      #pragma unroll
      for (int i = 0; i < 4; ++i) acc[i] += As[ty + 8 * i][k2] * bv;
    }
    __syncthreads();
  }
  float bb = bias[cb + tx];
  #pragma unroll
  for (int i = 0; i < 4; ++i)
    C[(rb + ty + 8 * i) * 512 + cb + tx] = acc[i] + bb;
}

// ---------------------------------------------------------------------------
// row softmax in place (one wave per row)
// ---------------------------------------------------------------------------
__global__ __launch_bounds__(64) void k_softmax_rows(float* __restrict__ W) {
  const int r = blockIdx.x, t = threadIdx.x;
  float* row = W + (size_t)r * 512;
  float v[8];
  float mx = -3.4e38f;
  #pragma unroll
  for (int i = 0; i < 8; ++i) { v[i] = row[t + 64 * i]; mx = fmaxf(mx, v[i]); }
  for (int m = 1; m < 64; m <<= 1) mx = fmaxf(mx, __shfl_xor(mx, m));
  float s = 0.f;
  #pragma unroll
  for (int i = 0; i < 8; ++i) { v[i] = expf(v[i] - mx); s += v[i]; }
  for (int m = 1; m < 64; m <<= 1) s += __shfl_xor(s, m);
  float inv = 1.0f / s;
  #pragma unroll
  for (int i = 0; i < 8; ++i) row[t + 64 * i] = v[i] * inv;
}

// ---------------------------------------------------------------------------
// S = I - h*W ; init eigen scalars
// ---------------------------------------------------------------------------
__global__ __launch_bounds__(256) void k_init_S(float* __restrict__ wsf) {
  const int idx = blockIdx.x * 256 + threadIdx.x;
  const int i = idx >> 9, j = idx & 511;
  float w = wsf[OFF_W + idx];
  wsf[OFF_SA + idx] = ((i == j) ? 1.0f : 0.0f) - EIG_H * w;
  if (idx == 0) {
    wsf[OFF_SC + 0] = 0.0f;   // G
    wsf[OFF_SC + 1] = 1.0f;   // inv_m
    ((unsigned int*)(wsf + OFF_SC))[8] = 0u;   // m_bits
  }
}

// ---------------------------------------------------------------------------
// C = (s*A)*(s*A), s = scal[1]; atomic max-abs into mbits
// ---------------------------------------------------------------------------
__global__ __launch_bounds__(256) void k_gemm_square(
    const float* __restrict__ A, float* __restrict__ C,
    const float* __restrict__ scal, unsigned int* __restrict__ mbits) {
  __shared__ float As[32][33], Bs[32][33];
  const int tx = threadIdx.x & 31, ty = threadIdx.x >> 5;
  const int rb = blockIdx.y * 32, cb = blockIdx.x * 32;
  float acc[4] = {0.f, 0.f, 0.f, 0.f};
  for (int kk = 0; kk < 512; kk += 32) {
    for (int idx = threadIdx.x; idx < 1024; idx += 256) {
      int r = idx >> 5, c = idx & 31;
      As[r][c] = A[(rb + r) * 512 + kk + c];
      Bs[r][c] = A[(kk + r) * 512 + cb + c];
    }
    __syncthreads();
    for (int k2 = 0; k2 < 32; ++k2) {
      float bv = Bs[k2][tx];
      #pragma unroll
      for (int i = 0; i < 4; ++i) acc[i] += As[ty + 8 * i][k2] * bv;
    }
    __syncthreads();
  }
  const float s = scal[1];
  const float s2 = s * s;
  float lmax = 0.f;
  #pragma unroll
  for (int i = 0; i < 4; ++i) {
    float v = acc[i] * s2;
    C[(rb + ty + 8 * i) * 512 + cb + tx] = v;
    lmax = fmaxf(lmax, fabsf(v));
  }
  for (int m = 1; m < 64; m <<= 1) lmax = fmaxf(lmax, __shfl_xor(lmax, m));
  if ((threadIdx.x & 63) == 0) atomicMax(mbits, __float_as_uint(lmax));
}

// ---------------------------------------------------------------------------
// G = 2G + ln m ; inv_m = 1/m ; m_bits = 0
// ---------------------------------------------------------------------------
__global__ void k_bookkeep(float* __restrict__ wsf) {
  unsigned int* mb = (unsigned int*)(wsf + OFF_SC) + 8;
  float m = fmaxf(__uint_as_float(*mb), 1e-30f);
  wsf[OFF_SC + 0] = 2.0f * wsf[OFF_SC + 0] + logf(m);
  wsf[OFF_SC + 1] = 1.0f / m;
  *mb = 0u;
}

// ---------------------------------------------------------------------------
// power-iter step: vout = (inv_m * S) * (vin / ||vin||); normAcc[p] = ||vout||^2
// ---------------------------------------------------------------------------
__global__ __launch_bounds__(64) void k_matvec(
    const float* __restrict__ S, const float* __restrict__ vin,
    float* __restrict__ vout, float* __restrict__ wsf, int p) {
  __shared__ float vv[512];
  const int t = threadIdx.x;
  const float invm = wsf[OFF_SC + 1];
  const float pn = (p == 0) ? 1.0f : fmaxf(wsf[OFF_NA + p - 1], 1e-30f);
  const float sc = invm / sqrtf(pn);
  for (int i = t; i < 512; i += 64) vv[i] = vin[i];
  __syncthreads();
  const int row = blockIdx.x * 64 + t;
  const float* rp = S + (size_t)row * 512;
  float acc = 0.f;
  for (int j = 0; j < 512; j += 4) {
    float4 a = *(const float4*)(rp + j);
    acc += a.x * vv[j] + a.y * vv[j + 1] + a.z * vv[j + 2] + a.w * vv[j + 3];
  }
  float y = acc * sc;
  vout[row] = y;
  float ss = y * y;
  for (int m = 1; m < 64; m <<= 1) ss += __shfl_xor(ss, m);
  if (t == 0) atomicAdd(&wsf[OFF_NA + p], ss);
}

// ---------------------------------------------------------------------------
// lam = 1 - minRe; minRe = (1 - exp(rate))/h ; rate = (slope + G)/2^k
// ---------------------------------------------------------------------------
__global__ void k_lamfin(float* __restrict__ wsf) {
  float slope = 0.f;
  for (int p = 8; p < 32; ++p) slope += 0.5f * logf(fmaxf(wsf[OFF_NA + p], 1e-30f));
  slope *= (1.0f / 24.0f);
  float rate = (slope + wsf[OFF_SC + 0]) * (1.0f / 16384.0f);
  float minre = (1.0f - expf(rate)) * (1.0f / EIG_H);
  float lam = 1.0f - minre;
  wsf[OFF_SC + 2] = lam;
  wsf[OFF_SC + 3] = 2.0f / lam - 1.0f;  // a  (Lt = a*I - c*W)
  wsf[OFF_SC + 4] = 2.0f / lam;         // c
}

// ---------------------------------------------------------------------------
// colsums of C1 = a*I - c*W and C2 = 2*C1 o C1 - I
// ---------------------------------------------------------------------------
__global__ __launch_bounds__(64) void k_colsum(const float* __restrict__ W,
                                               float* __restrict__ wsf) {
  const int m = blockIdx.x * 64 + threadIdx.x;
  float s1 = 0.f, s2 = 0.f;
  for (int n = 0; n < 512; ++n) {
    float w = W[n * 512 + m];
    s1 += w; s2 += w * w;
  }
  float wmm = W[m * 512 + m];
  float a = wsf[OFF_SC + 3], c = wsf[OFF_SC + 4];
  wsf[OFF_CS1 + m] = a - c * s1;
  wsf[OFF_CS2 + m] = 2.0f * (c * c * s2 + a * a - 2.0f * a * c * wmm) - 1.0f;
}

// ---------------------------------------------------------------------------
// wx = x2d(768x512) @ W(512x512)  (NN gemm)
// ---------------------------------------------------------------------------
__global__ __launch_bounds__(256) void k_gemm_wx(
    const float* __restrict__ A, const float* __restrict__ Bm,
    float* __restrict__ C) {
  __shared__ float As[32][33], Bs[32][33];
  const int tx = threadIdx.x & 31, ty = threadIdx.x >> 5;
  const int rb = blockIdx.y * 32, cb = blockIdx.x * 32;
  float acc[4] = {0.f, 0.f, 0.f, 0.f};
  for (int kk = 0; kk < 512; kk += 32) {
    for (int idx = threadIdx.x; idx < 1024; idx += 256) {
      int r = idx >> 5, c = idx & 31;
      As[r][c] = A[(rb + r) * 512 + kk + c];
      Bs[r][c] = Bm[(kk + r) * 512 + cb + c];
    }
    __syncthreads();
    for (int k2 = 0; k2 < 32; ++k2) {
      float bv = Bs[k2][tx];
      #pragma unroll
      for (int i = 0; i < 4; ++i) acc[i] += As[ty + 8 * i][k2] * bv;
    }
    __syncthreads();
  }
  #pragma unroll
  for (int i = 0; i < 4; ++i)
    C[(rb + ty + 8 * i) * 512 + cb + tx] = acc[i];
}

// ---------------------------------------------------------------------------
// y1=x@C1, y2=x@C2, z1=wx@C1, z2=wx@C2   (C_k built on the fly from W)
// ---------------------------------------------------------------------------
__global__ __launch_bounds__(256) void k_gemm_yz(
    const float* __restrict__ X, const float* __restrict__ WX,
    const float* __restrict__ W, const float* __restrict__ sc,
    float* __restrict__ y1, float* __restrict__ y2,
    float* __restrict__ z1, float* __restrict__ z2) {
  __shared__ float Xs[32][33], Ms[32][33], C1s[32][33], C2s[32][33];
  const int tx = threadIdx.x & 31, ty = threadIdx.x >> 5;
  const int rb = blockIdx.y * 32, cb = blockIdx.x * 32;
  const float a = sc[3], c = sc[4];
  float ay1[4] = {0,0,0,0}, ay2[4] = {0,0,0,0}, az1[4] = {0,0,0,0}, az2[4] = {0,0,0,0};
  for (int kk = 0; kk < 512; kk += 32) {
    for (int idx = threadIdx.x; idx < 1024; idx += 256) {
      int r = idx >> 5, cc = idx & 31;
      Xs[r][cc] = X[(rb + r) * 512 + kk + cc];
      Ms[r][cc] = WX[(rb + r) * 512 + kk + cc];
      float w = W[(kk + r) * 512 + cb + cc];
      float dl = ((kk + r) == (cb + cc)) ? 1.0f : 0.0f;
      float c1 = a * dl - c * w;
      C1s[r][cc] = c1;
      C2s[r][cc] = 2.0f * c1 * c1 - dl;
    }
    __syncthreads();
    for (int k2 = 0; k2 < 32; ++k2) {
      float b1 = C1s[k2][tx], b2 = C2s[k2][tx];
      #pragma unroll
      for (int i = 0; i < 4; ++i) {
        float xv = Xs[ty + 8 * i][k2];
        float wv = Ms[ty + 8 * i][k2];
        ay1[i] += xv * b1; ay2[i] += xv * b2;
        az1[i] += wv * b1; az2[i] += wv * b2;
      }
    }
    __syncthreads();
  }
  #pragma unroll
  for (int i = 0; i < 4; ++i) {
    int off = (rb + ty + 8 * i) * 512 + cb + tx;
    y1[off] = ay1[i]; y2[off] = ay2[i];
    z1[off] = az1[i]; z2[off] = az2[i];
  }
}

// ---------------------------------------------------------------------------
// temporal branch: one block per sequence (b,n). 256 threads.
// ---------------------------------------------------------------------------
#define BIGP 257
#define BIG(l, c) big[(l) * BIGP + (c)]

__device__ __forceinline__ void series_decomp(float (*h)[64], int lb, int e) {
  float ma[6];
  #pragma unroll
  for (int i = 0; i < 6; ++i) {
    int l = 4 * i + lb;
    float s = 0.f;
    #pragma unroll
    for (int j = -12; j <= 12; ++j) {
      int jj = l + j;
      jj = jj < 0 ? 0 : (jj > 23 ? 23 : jj);
      s += h[jj][e];
    }
    ma[i] = s * (1.0f / 25.0f);
  }
  __syncthreads();
  #pragma unroll
  for (int i = 0; i < 6; ++i) h[4 * i + lb][e] -= ma[i];
  __syncthreads();
}

__global__ __launch_bounds__(256) void k_temporal(
    const float* __restrict__ x, const float* __restrict__ pe,
    const float* __restrict__ wq, const float* __restrict__ bq,
    const float* __restrict__ wk, const float* __restrict__ bk,
    const float* __restrict__ wv, const float* __restrict__ bv,
    const float* __restrict__ wo, const float* __restrict__ bo,
    const float* __restrict__ c1w, const float* __restrict__ c1b,
    const float* __restrict__ c2w, const float* __restrict__ c2b,
    const float* __restrict__ ng, const float* __restrict__ nbv,
    const float* __restrict__ decw, const float* __restrict__ decb,
    float* __restrict__ trelu) {
  __shared__ float h[24][64];
  __shared__ float big[24 * BIGP];     // q|k|v|attn columns, then FF y
  __shared__ float xs[24];
  __shared__ float pc[576];
  __shared__ float corr[24];
  __shared__ float wsm[3];
  __shared__ int dly[3];
  __shared__ float mu[24], rsd[24], cmean[64], pr[192];

  const int t = threadIdx.x;
  const int s = blockIdx.x;
  const int b = s >> 9, n = s & 511;
  const int e = t & 63;
  const int lb = t >> 6;   // 0..3

  if (t < 24) xs[t] = x[(b * 24 + t) * 512 + n];
  __syncthreads();
  #pragma unroll
  for (int i = 0; i < 6; ++i) {
    int l = 4 * i + lb;
    h[l][e] = xs[l] + pe[l * 64 + e];
  }
  __syncthreads();

  for (int layer = 0; layer < 2; ++layer) {
    // ---- Q,K,V projections ----
    {
      float aq[6], ak[6], av[6];
      #pragma unroll
      for (int i = 0; i < 6; ++i) { aq[i] = bq[e]; ak[i] = bk[e]; av[i] = bv[e]; }
      for (int d = 0; d < 64; ++d) {
        float wqv = wq[e * 64 + d], wkv = wk[e * 64 + d], wvv = wv[e * 64 + d];
        #pragma unroll
        for (int i = 0; i < 6; ++i) {
          float hv = h[4 * i + lb][d];
          aq[i] += hv * wqv; ak[i] += hv * wkv; av[i] += hv * wvv;
        }
      }
      #pragma unroll
      for (int i = 0; i < 6; ++i) {
        int l = 4 * i + lb;
        BIG(l, e) = aq[i];
        BIG(l, 64 + e) = ak[i];
        BIG(l, 128 + e) = av[i];
      }
    }
    __syncthreads();
    // ---- circular correlation: corr[tau] = (1/64) sum_l <q_l, k_{(l-tau)%24}> ----
    for (int p = t; p < 576; p += 256) {
      int tau = p / 24;
      int l = p - tau * 24;
      int l2 = l - tau; if (l2 < 0) l2 += 24;
      float ssum = 0.f;
      #pragma unroll
      for (int d = 0; d < 64; ++d) ssum += BIG(l, d) * BIG(l2, 64 + d);
      pc[p] = ssum;
    }
    __syncthreads();
    if (t < 24) {
      float ssum = 0.f;
      #pragma unroll
      for (int l = 0; l < 24; ++l) ssum += pc[t * 24 + l];
      corr[t] = ssum * (1.0f / 64.0f);
    }
    __syncthreads();
    if (t == 0) {
      int i0 = 0, i1 = 0, i2 = 0;
      float v0 = -3.4e38f, v1 = -3.4e38f, v2 = -3.4e38f;
      for (int j = 0; j < 24; ++j) { float v = corr[j]; if (v > v0) { v0 = v; i0 = j; } }
      for (int j = 0; j < 24; ++j) { if (j == i0) continue; float v = corr[j]; if (v > v1) { v1 = v; i1 = j; } }
      for (int j = 0; j < 24; ++j) { if (j == i0 || j == i1) continue; float v = corr[j]; if (v > v2) { v2 = v; i2 = j; } }
      float e1 = expf(v1 - v0), e2 = expf(v2 - v0);
      float inv = 1.0f / (1.0f + e1 + e2);
      wsm[0] = inv; wsm[1] = e1 * inv; wsm[2] = e2 * inv;
      dly[0] = i0; dly[1] = i1; dly[2] = i2;
    }
    __syncthreads();
    // ---- delay aggregation ----
    {
      float w0 = wsm[0], w1 = wsm[1], w2 = wsm[2];
      int d0 = dly[0], d1 = dly[1], d2 = dly[2];
      #pragma unroll
      for (int i = 0; i < 6; ++i) {
        int l = 4 * i + lb;
        int l0 = l + d0; if (l0 >= 24) l0 -= 24;
        int l1_ = l + d1; if (l1_ >= 24) l1_ -= 24;
        int l2_ = l + d2; if (l2_ >= 24) l2_ -= 24;
        BIG(l, 192 + e) = w0 * BIG(l0, 128 + e) + w1 * BIG(l1_, 128 + e) + w2 * BIG(l2_, 128 + e);
      }
    }
    __syncthreads();
    // ---- O projection + residual ----
    {
      float ao[6];
      #pragma unroll
      for (int i = 0; i < 6; ++i) ao[i] = bo[e];
      for (int d = 0; d < 64; ++d) {
        float wov = wo[e * 64 + d];
        #pragma unroll
        for (int i = 0; i < 6; ++i) ao[i] += BIG(4 * i + lb, 192 + d) * wov;
      }
      #pragma unroll
      for (int i = 0; i < 6; ++i) h[4 * i + lb][e] += ao[i];
    }
    __syncthreads();
    series_decomp(h, lb, e);
    // ---- FF conv1: y[l][f] with f = t ----
    {
      float acc[24];
      float bb = c1b[t];
      #pragma unroll
      for (int l = 0; l < 24; ++l) acc[l] = bb;
      for (int d = 0; d < 64; ++d) {
        float wvv = c1w[t * 64 + d];
        #pragma unroll
        for (int l = 0; l < 24; ++l) acc[l] += h[l][d] * wvv;
      }
      #pragma unroll
      for (int l = 0; l < 24; ++l) BIG(l, t) = fmaxf(acc[l], 0.0f);
    }
    __syncthreads();
    // ---- FF conv2 + residual ----
    {
      float ac[6];
      #pragma unroll
      for (int i = 0; i < 6; ++i) ac[i] = c2b[e];
      for (int f = 0; f < 256; ++f) {
        float wvv = c2w[e * 256 + f];
        #pragma unroll
        for (int i = 0; i < 6; ++i) ac[i] += BIG(4 * i + lb, f) * wvv;
      }
      #pragma unroll
      for (int i = 0; i < 6; ++i) h[4 * i + lb][e] += ac[i];
    }
    __syncthreads();
    series_decomp(h, lb, e);
  }

  // ---- LayerNorm over D ----
  if (t < 24) {
    float sm = 0.f;
    for (int d = 0; d < 64; ++d) sm += h[t][d];
    float m_ = sm * (1.0f / 64.0f);
    float vs = 0.f;
    for (int d = 0; d < 64; ++d) { float df = h[t][d] - m_; vs += df * df; }
    mu[t] = m_;
    rsd[t] = 1.0f / sqrtf(vs * (1.0f / 64.0f) + 1e-5f);
  }
  __syncthreads();
  #pragma unroll
  for (int i = 0; i < 6; ++i) {
    int l = 4 * i + lb;
    h[l][e] = (h[l][e] - mu[l]) * rsd[l] * ng[e] + nbv[e];
  }
  __syncthreads();
  // ---- my_Layernorm: subtract column (L) mean ----
  if (t < 64) {
    float sm = 0.f;
    for (int l = 0; l < 24; ++l) sm += h[l][t];
    cmean[t] = sm * (1.0f / 24.0f);
  }
  __syncthreads();
  #pragma unroll
  for (int i = 0; i < 6; ++i) h[4 * i + lb][e] -= cmean[e];
  __syncthreads();
  // ---- dec head: t_relu[u] = relu(dec_b[u] + sum_j flat[j]*dec_w[u,j]) ----
  {
    if (t < 192) {
      int u = t >> 4, ch = t & 15;
      const float* hf = &h[0][0] + ch * 96;
      const float* dw = decw + u * 1536 + ch * 96;
      float part = 0.f;
      for (int j = 0; j < 96; ++j) part += hf[j] * dw[j];
      pr[t] = part;
    }
    __syncthreads();
    if (t < 12) {
      float ssum = decb[t];
      #pragma unroll
      for (int c_ = 0; c_ < 16; ++c_) ssum += pr[t * 16 + c_];
      trelu[s * 12 + t] = fmaxf(ssum, 0.0f);
    }
  }
}

// ---------------------------------------------------------------------------
// final: spatial assembly + slin + combine with temporal, write FLOAT32 output
// one block per (b, node m); 64 threads = output channel o
// ---------------------------------------------------------------------------
__global__ __launch_bounds__(64) void k_final(
    const float* __restrict__ x, const float* __restrict__ wx,
    const float* __restrict__ y1, const float* __restrict__ y2,
    const float* __restrict__ z1, const float* __restrict__ z2,
    const float* __restrict__ cs1, const float* __restrict__ cs2,
    const float* __restrict__ trelu,
    const float* __restrict__ alpha, const float* __restrict__ beta,
    const float* __restrict__ theta,
    const float* __restrict__ slinw, const float* __restrict__ slinb,
    const float* __restrict__ tlinw, const float* __restrict__ tlinb,
    float* __restrict__ out) {
  __shared__ float ly0[24], ly1[24], ly2[24], lz0[24], lz1[24], lz2[24];
  __shared__ float ltr[12], lsw[288];
  const int blk = blockIdx.x;
  const int b = blk >> 9, m = blk & 511;
  const int t = threadIdx.x;
  if (t < 24) {
    int row = (b * 24 + t) * 512 + m;
    ly0[t] = x[row];  ly1[t] = y1[row]; ly2[t] = y2[row];
    lz0[t] = wx[row]; lz1[t] = z1[row]; lz2[t] = z2[row];
  }
  if (t >= 48 && t < 60) ltr[t - 48] = trelu[(b * 512 + m) * 12 + (t - 48)];
  for (int i = t; i < 288; i += 64) lsw[i] = slinw[i];
  __syncthreads();
  const int o = t;
  const float at = alpha[0] + alpha[1] * cs1[m] + alpha[2] * cs2[m];
  const float b0 = beta[o], b1 = beta[64 + o], b2 = beta[128 + o];
  const float t0 = theta[o], t1 = theta[64 + o], t2 = theta[128 + o];
  float so[12];
  #pragma unroll
  for (int u = 0; u < 12; ++u) so[u] = 0.f;
  for (int tt = 0; tt < 24; ++tt) {
    float v = at + b0 * ly0[tt] + b1 * ly1[tt] + b2 * ly2[tt]
                 + t0 * lz0[tt] + t1 * lz1[tt] + t2 * lz2[tt];
    v = fmaxf(v, 0.0f);
    #pragma unroll
    for (int u = 0; u < 12; ++u) so[u] += lsw[u * 24 + tt] * v;
  }
  const float tw = tlinw[o], tb = tlinb[o];
  #pragma unroll
  for (int u = 0; u < 12; ++u) {
    float sval = so[u] + slinb[u];
    float tval = tw * ltr[u] + tb;
    float r = fmaxf(sval * tval, 0.0f);
    out[(((size_t)b * 12 + u) * 512 + m) * 64 + o] = r;   // FLOAT32 store
  }
}

// ===========================================================================
extern "C" void kernel_launch(void* const* d_in, const int* in_sizes, int n_in,
                              void* d_out, int out_size, void* d_ws, size_t ws_size,
                              hipStream_t stream) {
  (void)in_sizes; (void)n_in; (void)out_size; (void)ws_size;
  const float* s_w    = (const float*)d_in[0];
  const float* x      = (const float*)d_in[1];
  const float* swnn_w = (const float*)d_in[2];
  const float* swnn_b = (const float*)d_in[3];
  const float* alpha  = (const float*)d_in[4];
  const float* beta   = (const float*)d_in[5];
  const float* theta  = (const float*)d_in[6];
  const float* wq = (const float*)d_in[7];  const float* bq = (const float*)d_in[8];
  const float* wk = (const float*)d_in[9];  const float* bk = (const float*)d_in[10];
  const float* wv = (const float*)d_in[11]; const float* bv = (const float*)d_in[12];
  const float* wo = (const float*)d_in[13]; const float* bo = (const float*)d_in[14];
  const float* c1w = (const float*)d_in[15]; const float* c1b = (const float*)d_in[16];
  const float* c2w = (const float*)d_in[17]; const float* c2b = (const float*)d_in[18];
  const float* ng  = (const float*)d_in[19]; const float* nb  = (const float*)d_in[20];
  const float* decw = (const float*)d_in[21]; const float* decb = (const float*)d_in[22];
  const float* slinw = (const float*)d_in[23]; const float* slinb = (const float*)d_in[24];
  const float* tlinw = (const float*)d_in[25]; const float* tlinb = (const float*)d_in[26];

  float* wsf = (float*)d_ws;
  float* out = (float*)d_out;

  float* Wm = wsf + OFF_W;
  float* Sa = wsf + OFF_SA;
  float* Sb = wsf + OFF_SB;
  unsigned int* mbits = (unsigned int*)(wsf + OFF_SC) + 8;
  const float* scal = wsf + OFF_SC;

  k_prep<<<1, 256, 0, stream>>>(wsf);
  k_gemm_logits<<<dim3(16, 16), 256, 0, stream>>>(s_w, swnn_w, swnn_b, Wm);
  k_softmax_rows<<<512, 64, 0, stream>>>(Wm);

  // temporal branch (independent of spatial; needs pe from prep)
  k_temporal<<<16384, 256, 0, stream>>>(x, wsf + OFF_PE, wq, bq, wk, bk, wv, bv,
                                        wo, bo, c1w, c1b, c2w, c2b, ng, nb,
                                        decw, decb, wsf + OFF_TR);

  // ---- eigen: scaling-squaring + power iteration ----
  k_init_S<<<1024, 256, 0, stream>>>(wsf);
  float* cur = Sa;
  float* nxt = Sb;
  for (int j = 0; j < EIG_K; ++j) {
    k_gemm_square<<<dim3(16, 16), 256, 0, stream>>>(cur, nxt, scal, mbits);
    k_bookkeep<<<1, 1, 0, stream>>>(wsf);
    float* tmp = cur; cur = nxt; nxt = tmp;
  }
  float* va = wsf + OFF_V0;
  float* vb = wsf + OFF_V1;
  for (int p = 0; p < MV_STEPS; ++p) {
    k_matvec<<<8, 64, 0, stream>>>(cur, va, vb, wsf, p);
    float* tmp = va; va = vb; vb = tmp;
  }
  k_lamfin<<<1, 1, 0, stream>>>(wsf);

  // ---- spatial branch ----
  k_colsum<<<8, 64, 0, stream>>>(Wm, wsf);
  k_gemm_wx<<<dim3(16, 24), 256, 0, stream>>>(x, Wm, wsf + OFF_WX);
  k_gemm_yz<<<dim3(16, 24), 256, 0, stream>>>(x, wsf + OFF_WX, Wm, scal,
                                              wsf + OFF_Y1, wsf + OFF_Y2,
                                              wsf + OFF_Z1, wsf + OFF_Z2);
  // ---- final combine ----
  k_final<<<16384, 64, 0, stream>>>(x, wsf + OFF_WX, wsf + OFF_Y1, wsf + OFF_Y2,
                                    wsf + OFF_Z1, wsf + OFF_Z2,
                                    wsf + OFF_CS1, wsf + OFF_CS2, wsf + OFF_TR,
                                    alpha, beta, theta, slinw, slinb,
                                    tlinw, tlinb, out);
}

// Round 7
// 4467.940 us; speedup vs baseline: 1.7818x; 1.7818x over previous
//
#include <hip/hip_runtime.h>
#include <hip/hip_bf16.h>
#include <math.h>

// ============================================================================
// GSTRGCT full forward.  N=512 B=32 T_IN=24 T_OUT=12 C_OUT=64 D=64 K=3
// LAYERS=2 DFF=256 MA=25 top_k=3. Output FLOAT32.
// ============================================================================

// ---------------- workspace layout (floats) ----------------
static const size_t OFF_W   = 0;
static const size_t OFF_SA  = OFF_W  + 512*512;
static const size_t OFF_SB  = OFF_SA + 512*512;
static const size_t OFF_WX  = OFF_SB + 512*512;
static const size_t OFF_Y1  = OFF_WX + 768*512;
static const size_t OFF_Y2  = OFF_Y1 + 768*512;
static const size_t OFF_Z1  = OFF_Y2 + 768*512;
static const size_t OFF_Z2  = OFF_Z1 + 768*512;
static const size_t OFF_TR  = OFF_Z2 + 768*512;       // 16384*12
static const size_t OFF_PE  = OFF_TR + 16384*12;      // 24*64
static const size_t OFF_CS1 = OFF_PE + 24*64;
static const size_t OFF_CS2 = OFF_CS1 + 512;
static const size_t OFF_V0  = OFF_CS2 + 512;
static const size_t OFF_V1  = OFF_V0 + 512;
static const size_t OFF_NA  = OFF_V1 + 512;           // 64
static const size_t OFF_SC  = OFF_NA + 64;            // 16 scalars
static const size_t OFF_M   = OFF_SC + 16;            // 64*64  Wq^T Wk
static const size_t OFF_PT  = OFF_M  + 4096;          // 64*64  (Wo Wv)^T as [d][e]
static const size_t OFF_C1T = OFF_PT + 4096;          // 64*256 c1w^T [d][f]
static const size_t OFF_C2T = OFF_C1T + 16384;        // 256*64 c2w^T [f][e]
static const size_t OFF_BVO = OFF_C2T + 16384;        // 64

#define EIG_H 0.125f
#define EIG_K 14        /* t = h*2^14 = 2048 (validated config, round 3) */
#define MV_STEPS 32

// ---------------------------------------------------------------------------
// prep: PE table, power-iter seed, normAcc zero
// ---------------------------------------------------------------------------
__global__ __launch_bounds__(256) void k_prep(float* __restrict__ wsf) {
  const int t = threadIdx.x;
  for (int idx = t; idx < 24 * 64; idx += 256) {
    int l = idx >> 6, d = idx & 63;
    int i = d >> 1;
    float div = expf((float)(2 * i) * (-9.210340371976184f / 64.0f));
    float ang = (float)l * div;
    wsf[OFF_PE + idx] = (d & 1) ? cosf(ang) : sinf(ang);
  }
  for (int idx = t; idx < 512; idx += 256)
    wsf[OFF_V0 + idx] = sinf((float)idx * 12.9898f + 0.5f) + 0.01f;
  for (int idx = t; idx < 64; idx += 256)
    wsf[OFF_NA + idx] = 0.0f;
}

// ---------------------------------------------------------------------------
// weight prep: M = Wq^T Wk ; PT[d][e] = (Wo Wv)[e][d] ; transposes ; bvo
// ---------------------------------------------------------------------------
__global__ __launch_bounds__(256) void k_wprep(
    const float* __restrict__ wq, const float* __restrict__ wk,
    const float* __restrict__ wv, const float* __restrict__ wo,
    const float* __restrict__ bv, const float* __restrict__ bo,
    const float* __restrict__ c1w, const float* __restrict__ c2w,
    float* __restrict__ wsf) {
  const int blk = blockIdx.x, t = threadIdx.x;
  if (blk == 0) {
    for (int i = 0; i < 16; ++i) {
      int idx = i * 256 + t;
      int d = idx >> 6, dp = idx & 63;
      float s = 0.f;
      for (int e = 0; e < 64; ++e) s += wq[e * 64 + d] * wk[e * 64 + dp];
      wsf[OFF_M + idx] = s;
    }
    if (t < 64) {
      float s = bo[t];
      for (int f = 0; f < 64; ++f) s += wo[t * 64 + f] * bv[f];
      wsf[OFF_BVO + t] = s;
    }
  } else if (blk == 1) {
    for (int i = 0; i < 16; ++i) {
      int idx = i * 256 + t;
      int d = idx >> 6, e = idx & 63;
      float s = 0.f;
      for (int f = 0; f < 64; ++f) s += wo[e * 64 + f] * wv[f * 64 + d];
      wsf[OFF_PT + idx] = s;
    }
  } else if (blk < 4) {
    int base = (blk - 2) * 8192;
    for (int i = 0; i < 32; ++i) {
      int idx = base + i * 256 + t;
      int d = idx >> 8, f = idx & 255;
      wsf[OFF_C1T + idx] = c1w[f * 64 + d];
    }
  } else {
    int base = (blk - 4) * 8192;
    for (int i = 0; i < 32; ++i) {
      int idx = base + i * 256 + t;
      int f = idx >> 6, e = idx & 63;
      wsf[OFF_C2T + idx] = c2w[e * 256 + f];
    }
  }
}

// ---------------------------------------------------------------------------
// logits = s_w @ swnn_w^T + swnn_b
// ---------------------------------------------------------------------------
__global__ __launch_bounds__(256) void k_gemm_logits(
    const float* __restrict__ A, const float* __restrict__ Bm,
    const float* __restrict__ bias, float* __restrict__ C) {
  __shared__ float As[32][33], Bs[32][33];
  const int tx = threadIdx.x & 31, ty = threadIdx.x >> 5;
  const int rb = blockIdx.y * 32, cb = blockIdx.x * 32;
  float acc[4] = {0.f, 0.f, 0.f, 0.f};
  for (int kk = 0; kk < 512; kk += 32) {
    for (int idx = threadIdx.x; idx < 1024; idx += 256) {
      int r = idx >> 5, c = idx & 31;
      As[r][c] = A[(rb + r) * 512 + kk + c];
      Bs[c][r] = Bm[(cb + r) * 512 + kk + c];
    }
    __syncthreads();
    for (int k2 = 0; k2 < 32; ++k2) {
      float bvv = Bs[k2][tx];
      #pragma unroll
      for (int i = 0; i < 4; ++i) acc[i] += As[ty + 8 * i][k2] * bvv;
    }
    __syncthreads();
  }
  float bb = bias[cb + tx];
  #pragma unroll
  for (int i = 0; i < 4; ++i)
    C[(rb + ty + 8 * i) * 512 + cb + tx] = acc[i] + bb;
}

__global__ __launch_bounds__(64) void k_softmax_rows(float* __restrict__ W) {
  const int r = blockIdx.x, t = threadIdx.x;
  float* row = W + (size_t)r * 512;
  float v[8];
  float mx = -3.4e38f;
  #pragma unroll
  for (int i = 0; i < 8; ++i) { v[i] = row[t + 64 * i]; mx = fmaxf(mx, v[i]); }
  for (int m = 1; m < 64; m <<= 1) mx = fmaxf(mx, __shfl_xor(mx, m));
  float s = 0.f;
  #pragma unroll
  for (int i = 0; i < 8; ++i) { v[i] = expf(v[i] - mx); s += v[i]; }
  for (int m = 1; m < 64; m <<= 1) s += __shfl_xor(s, m);
  float inv = 1.0f / s;
  #pragma unroll
  for (int i = 0; i < 8; ++i) row[t + 64 * i] = v[i] * inv;
}

__global__ __launch_bounds__(256) void k_init_S(float* __restrict__ wsf) {
  const int idx = blockIdx.x * 256 + threadIdx.x;
  const int i = idx >> 9, j = idx & 511;
  float w = wsf[OFF_W + idx];
  wsf[OFF_SA + idx] = ((i == j) ? 1.0f : 0.0f) - EIG_H * w;
  if (idx == 0) {
    wsf[OFF_SC + 0] = 0.0f;
    wsf[OFF_SC + 1] = 1.0f;
    ((unsigned int*)(wsf + OFF_SC))[8] = 0u;
  }
}

__global__ __launch_bounds__(256) void k_gemm_square(
    const float* __restrict__ A, float* __restrict__ C,
    const float* __restrict__ scal, unsigned int* __restrict__ mbits) {
  __shared__ float As[32][33], Bs[32][33];
  const int tx = threadIdx.x & 31, ty = threadIdx.x >> 5;
  const int rb = blockIdx.y * 32, cb = blockIdx.x * 32;
  float acc[4] = {0.f, 0.f, 0.f, 0.f};
  for (int kk = 0; kk < 512; kk += 32) {
    for (int idx = threadIdx.x; idx < 1024; idx += 256) {
      int r = idx >> 5, c = idx & 31;
      As[r][c] = A[(rb + r) * 512 + kk + c];
      Bs[r][c] = A[(kk + r) * 512 + cb + c];
    }
    __syncthreads();
    for (int k2 = 0; k2 < 32; ++k2) {
      float bvv = Bs[k2][tx];
      #pragma unroll
      for (int i = 0; i < 4; ++i) acc[i] += As[ty + 8 * i][k2] * bvv;
    }
    __syncthreads();
  }
  const float s = scal[1];
  const float s2 = s * s;
  float lmax = 0.f;
  #pragma unroll
  for (int i = 0; i < 4; ++i) {
    float v = acc[i] * s2;
    C[(rb + ty + 8 * i) * 512 + cb + tx] = v;
    lmax = fmaxf(lmax, fabsf(v));
  }
  for (int m = 1; m < 64; m <<= 1) lmax = fmaxf(lmax, __shfl_xor(lmax, m));
  if ((threadIdx.x & 63) == 0) atomicMax(mbits, __float_as_uint(lmax));
}

__global__ void k_bookkeep(float* __restrict__ wsf) {
  unsigned int* mb = (unsigned int*)(wsf + OFF_SC) + 8;
  float m = fmaxf(__uint_as_float(*mb), 1e-30f);
  wsf[OFF_SC + 0] = 2.0f * wsf[OFF_SC + 0] + logf(m);
  wsf[OFF_SC + 1] = 1.0f / m;
  *mb = 0u;
}

__global__ __launch_bounds__(64) void k_matvec(
    const float* __restrict__ S, const float* __restrict__ vin,
    float* __restrict__ vout, float* __restrict__ wsf, int p) {
  __shared__ float vv[512];
  const int t = threadIdx.x;
  const float invm = wsf[OFF_SC + 1];
  const float pn = (p == 0) ? 1.0f : fmaxf(wsf[OFF_NA + p - 1], 1e-30f);
  const float sc = invm / sqrtf(pn);
  for (int i = t; i < 512; i += 64) vv[i] = vin[i];
  __syncthreads();
  const int row = blockIdx.x * 64 + t;
  const float* rp = S + (size_t)row * 512;
  float acc = 0.f;
  for (int j = 0; j < 512; j += 4) {
    float4 a = *(const float4*)(rp + j);
    acc += a.x * vv[j] + a.y * vv[j + 1] + a.z * vv[j + 2] + a.w * vv[j + 3];
  }
  float y = acc * sc;
  vout[row] = y;
  float ss = y * y;
  for (int m = 1; m < 64; m <<= 1) ss += __shfl_xor(ss, m);
  if (t == 0) atomicAdd(&wsf[OFF_NA + p], ss);
}

__global__ void k_lamfin(float* __restrict__ wsf) {
  float slope = 0.f;
  for (int p = 8; p < 32; ++p) slope += 0.5f * logf(fmaxf(wsf[OFF_NA + p], 1e-30f));
  slope *= (1.0f / 24.0f);
  float rate = (slope + wsf[OFF_SC + 0]) * (1.0f / 16384.0f);
  float minre = (1.0f - expf(rate)) * (1.0f / EIG_H);
  float lam = 1.0f - minre;
  wsf[OFF_SC + 2] = lam;
  wsf[OFF_SC + 3] = 2.0f / lam - 1.0f;
  wsf[OFF_SC + 4] = 2.0f / lam;
}

__global__ __launch_bounds__(64) void k_colsum(const float* __restrict__ W,
                                               float* __restrict__ wsf) {
  const int m = blockIdx.x * 64 + threadIdx.x;
  float s1 = 0.f, s2 = 0.f;
  for (int n = 0; n < 512; ++n) {
    float w = W[n * 512 + m];
    s1 += w; s2 += w * w;
  }
  float wmm = W[m * 512 + m];
  float a = wsf[OFF_SC + 3], c = wsf[OFF_SC + 4];
  wsf[OFF_CS1 + m] = a - c * s1;
  wsf[OFF_CS2 + m] = 2.0f * (c * c * s2 + a * a - 2.0f * a * c * wmm) - 1.0f;
}

__global__ __launch_bounds__(256) void k_gemm_wx(
    const float* __restrict__ A, const float* __restrict__ Bm,
    float* __restrict__ C) {
  __shared__ float As[32][33], Bs[32][33];
  const int tx = threadIdx.x & 31, ty = threadIdx.x >> 5;
  const int rb = blockIdx.y * 32, cb = blockIdx.x * 32;
  float acc[4] = {0.f, 0.f, 0.f, 0.f};
  for (int kk = 0; kk < 512; kk += 32) {
    for (int idx = threadIdx.x; idx < 1024; idx += 256) {
      int r = idx >> 5, c = idx & 31;
      As[r][c] = A[(rb + r) * 512 + kk + c];
      Bs[r][c] = Bm[(kk + r) * 512 + cb + c];
    }
    __syncthreads();
    for (int k2 = 0; k2 < 32; ++k2) {
      float bvv = Bs[k2][tx];
      #pragma unroll
      for (int i = 0; i < 4; ++i) acc[i] += As[ty + 8 * i][k2] * bvv;
    }
    __syncthreads();
  }
  #pragma unroll
  for (int i = 0; i < 4; ++i)
    C[(rb + ty + 8 * i) * 512 + cb + tx] = acc[i];
}

__global__ __launch_bounds__(256) void k_gemm_yz(
    const float* __restrict__ X, const float* __restrict__ WX,
    const float* __restrict__ W, const float* __restrict__ sc,
    float* __restrict__ y1, float* __restrict__ y2,
    float* __restrict__ z1, float* __restrict__ z2) {
  __shared__ float Xs[32][33], Ms[32][33], C1s[32][33], C2s[32][33];
  const int tx = threadIdx.x & 31, ty = threadIdx.x >> 5;
  const int rb = blockIdx.y * 32, cb = blockIdx.x * 32;
  const float a = sc[3], c = sc[4];
  float ay1[4] = {0,0,0,0}, ay2[4] = {0,0,0,0}, az1[4] = {0,0,0,0}, az2[4] = {0,0,0,0};
  for (int kk = 0; kk < 512; kk += 32) {
    for (int idx = threadIdx.x; idx < 1024; idx += 256) {
      int r = idx >> 5, cc = idx & 31;
      Xs[r][cc] = X[(rb + r) * 512 + kk + cc];
      Ms[r][cc] = WX[(rb + r) * 512 + kk + cc];
      float w = W[(kk + r) * 512 + cb + cc];
      float dl = ((kk + r) == (cb + cc)) ? 1.0f : 0.0f;
      float c1 = a * dl - c * w;
      C1s[r][cc] = c1;
      C2s[r][cc] = 2.0f * c1 * c1 - dl;
    }
    __syncthreads();
    for (int k2 = 0; k2 < 32; ++k2) {
      float b1 = C1s[k2][tx], b2 = C2s[k2][tx];
      #pragma unroll
      for (int i = 0; i < 4; ++i) {
        float xv = Xs[ty + 8 * i][k2];
        float wv = Ms[ty + 8 * i][k2];
        ay1[i] += xv * b1; ay2[i] += xv * b2;
        az1[i] += wv * b1; az2[i] += wv * b2;
      }
    }
    __syncthreads();
  }
  #pragma unroll
  for (int i = 0; i < 4; ++i) {
    int off = (rb + ty + 8 * i) * 512 + cb + tx;
    y1[off] = ay1[i]; y2[off] = ay2[i];
    z1[off] = az1[i]; z2[off] = az2[i];
  }
}

// ---------------------------------------------------------------------------
// temporal branch v3: 8 seqs/block, thread-per-row, uniform-address weights,
// FULL FP32 (delay aggregation done in h-space before the P matvec:
// sum_i w_i P h_{l+d_i} = P (sum_i w_i h_{l+d_i}) since P linear, sum w = 1).
// LDS ~53.7 KB -> 2 blocks/CU.
// ---------------------------------------------------------------------------
#define HSTR 65

__device__ __forceinline__ void decomp_block(float* hl, int r, int seq, int l,
                                             bool active) {
  float ma[64];
  if (active) {
    #pragma unroll
    for (int dc = 0; dc < 16; ++dc) {
      float s0 = 0.f, s1 = 0.f, s2 = 0.f, s3 = 0.f;
      for (int j = 0; j < 25; ++j) {
        int jj = l - 12 + j;
        jj = jj < 0 ? 0 : (jj > 23 ? 23 : jj);
        int bb = (seq * 24 + jj) * HSTR + dc * 4;
        s0 += hl[bb]; s1 += hl[bb + 1]; s2 += hl[bb + 2]; s3 += hl[bb + 3];
      }
      ma[dc * 4] = s0; ma[dc * 4 + 1] = s1; ma[dc * 4 + 2] = s2; ma[dc * 4 + 3] = s3;
    }
  }
  __syncthreads();
  if (active) {
    #pragma unroll
    for (int e = 0; e < 64; ++e) hl[r * HSTR + e] -= ma[e] * (1.0f / 25.0f);
  }
  __syncthreads();
}

__global__ __launch_bounds__(256, 2) void k_temporal2(
    const float* __restrict__ x, const float* __restrict__ pe,
    const float* __restrict__ Mw, const float* __restrict__ PTw,
    const float* __restrict__ C1T, const float* __restrict__ C2T,
    const float* __restrict__ bvo,
    const float* __restrict__ c1b, const float* __restrict__ c2b,
    const float* __restrict__ ng, const float* __restrict__ nbv,
    const float* __restrict__ decw, const float* __restrict__ decb,
    float* __restrict__ trelu) {
  __shared__ float hl[8 * 24 * HSTR];        // 49920 B
  __shared__ float corr_s[192];
  __shared__ float cmean_s[512];
  __shared__ float wsm_s[24];
  __shared__ int dly_s[24];
  __shared__ float pr_s[192];

  const int t = threadIdx.x;
  const int s0 = blockIdx.x * 8;
  const bool active = t < 192;
  const int r = t;
  const int seq = r / 24;
  const int l = r - seq * 24;
  const int gseq = s0 + seq;
  const int b = gseq >> 9, n = gseq & 511;

  // ---- init h = x + pe ----
  if (active) {
    float xv = x[(b * 24 + l) * 512 + n];
    const float4* per = (const float4*)(pe + l * 64);
    #pragma unroll
    for (int c = 0; c < 16; ++c) {
      float4 pv = per[c];
      int bb = r * HSTR + c * 4;
      hl[bb] = xv + pv.x; hl[bb + 1] = xv + pv.y;
      hl[bb + 2] = xv + pv.z; hl[bb + 3] = xv + pv.w;
    }
  }
  __syncthreads();

  for (int layer = 0; layer < 2; ++layer) {
    // ---- zero corr ----
    if (active) corr_s[t] = 0.f;
    __syncthreads();
    // ---- u = M^T h (own row), then corr partials ----
    {
      float u[64];
      #pragma unroll
      for (int e = 0; e < 64; ++e) u[e] = 0.f;
      if (active) {
        for (int d = 0; d < 64; ++d) {
          float hv = hl[r * HSTR + d];
          const float* Mr = Mw + d * 64;
          #pragma unroll
          for (int e = 0; e < 64; ++e) u[e] += hv * Mr[e];
        }
        for (int tau = 0; tau < 24; ++tau) {
          int l2 = l - tau; if (l2 < 0) l2 += 24;
          int bb = (seq * 24 + l2) * HSTR;
          float acc = 0.f;
          #pragma unroll
          for (int d = 0; d < 64; ++d) acc += u[d] * hl[bb + d];
          atomicAdd(&corr_s[seq * 24 + tau], acc * (1.0f / 64.0f));
        }
      }
    }
    __syncthreads();
    // ---- top-3 + softmax (per seq) ----
    if (t < 8) {
      const float* cr = corr_s + t * 24;
      int i0 = 0, i1 = 0, i2 = 0;
      float v0 = -3.4e38f, v1 = -3.4e38f, v2 = -3.4e38f;
      for (int j = 0; j < 24; ++j) { float v = cr[j]; if (v > v0) { v0 = v; i0 = j; } }
      for (int j = 0; j < 24; ++j) { if (j == i0) continue; float v = cr[j]; if (v > v1) { v1 = v; i1 = j; } }
      for (int j = 0; j < 24; ++j) { if (j == i0 || j == i1) continue; float v = cr[j]; if (v > v2) { v2 = v; i2 = j; } }
      float e1 = expf(v1 - v0), e2 = expf(v2 - v0);
      float inv = 1.0f / (1.0f + e1 + e2);
      wsm_s[t * 3] = inv; wsm_s[t * 3 + 1] = e1 * inv; wsm_s[t * 3 + 2] = e2 * inv;
      dly_s[t * 3] = i0; dly_s[t * 3 + 1] = i1; dly_s[t * 3 + 2] = i2;
    }
    __syncthreads();
    // ---- delay aggregation in h-space (fp32 exact): agg = sum w_i h_{l+d_i} ----
    float agg[64];
    if (active) {
      float w0 = wsm_s[seq * 3], w1 = wsm_s[seq * 3 + 1], w2 = wsm_s[seq * 3 + 2];
      int d0 = dly_s[seq * 3], d1 = dly_s[seq * 3 + 1], d2 = dly_s[seq * 3 + 2];
      int l0 = l + d0; if (l0 >= 24) l0 -= 24;
      int l1 = l + d1; if (l1 >= 24) l1 -= 24;
      int l2 = l + d2; if (l2 >= 24) l2 -= 24;
      int b0 = (seq * 24 + l0) * HSTR, b1 = (seq * 24 + l1) * HSTR, b2 = (seq * 24 + l2) * HSTR;
      #pragma unroll
      for (int d = 0; d < 64; ++d)
        agg[d] = w0 * hl[b0 + d] + w1 * hl[b1 + d] + w2 * hl[b2 + d];
    }
    __syncthreads();   // all reads of hl complete before any writes below
    // ---- h += P agg + bvo (own row) ----
    if (active) {
      float acc[64];
      #pragma unroll
      for (int e = 0; e < 64; ++e) acc[e] = 0.f;
      for (int d = 0; d < 64; ++d) {
        float av = agg[d];
        const float* Pr = PTw + d * 64;
        #pragma unroll
        for (int e = 0; e < 64; ++e) acc[e] += av * Pr[e];
      }
      #pragma unroll
      for (int e = 0; e < 64; ++e) hl[r * HSTR + e] += acc[e] + bvo[e];
    }
    __syncthreads();
    decomp_block(hl, r, seq, l, active);
    // ---- fused FF: conv1(relu) -> conv2, fp32 registers (own row) ----
    {
      float a2[64];
      #pragma unroll
      for (int e = 0; e < 64; ++e) a2[e] = 0.f;
      if (active) {
        for (int fc = 0; fc < 4; ++fc) {
          float y[64];
          #pragma unroll
          for (int f = 0; f < 64; ++f) y[f] = 0.f;
          for (int d = 0; d < 64; ++d) {
            float hv = hl[r * HSTR + d];
            const float* c1r = C1T + d * 256 + fc * 64;
            #pragma unroll
            for (int f = 0; f < 64; ++f) y[f] += hv * c1r[f];
          }
          #pragma unroll
          for (int f = 0; f < 64; ++f) y[f] = fmaxf(y[f] + c1b[fc * 64 + f], 0.0f);
          #pragma unroll
          for (int j = 0; j < 32; ++j) {
            float ylo = y[2 * j], yhi = y[2 * j + 1];
            const float* r0 = C2T + (fc * 64 + 2 * j) * 64;
            const float* r1 = r0 + 64;
            #pragma unroll
            for (int e = 0; e < 64; ++e) a2[e] += ylo * r0[e] + yhi * r1[e];
          }
        }
        #pragma unroll
        for (int e = 0; e < 64; ++e) hl[r * HSTR + e] += a2[e] + c2b[e];
      }
    }
    __syncthreads();
    decomp_block(hl, r, seq, l, active);
  }

  // ---- LayerNorm over D (own row) ----
  if (active) {
    float hr[64];
    #pragma unroll
    for (int e = 0; e < 64; ++e) hr[e] = hl[r * HSTR + e];
    float mu = 0.f;
    #pragma unroll
    for (int e = 0; e < 64; ++e) mu += hr[e];
    mu *= (1.0f / 64.0f);
    float vs = 0.f;
    #pragma unroll
    for (int e = 0; e < 64; ++e) { float d = hr[e] - mu; vs += d * d; }
    float rs = rsqrtf(vs * (1.0f / 64.0f) + 1e-5f);
    #pragma unroll
    for (int e = 0; e < 64; ++e)
      hl[r * HSTR + e] = (hr[e] - mu) * rs * ng[e] + nbv[e];
  }
  __syncthreads();
  // ---- my_Layernorm: subtract column mean over L ----
  for (int pass = 0; pass < 2; ++pass) {
    int idx = pass * 256 + t;
    int sq2 = idx >> 6, e2 = idx & 63;
    float s = 0.f;
    for (int ll = 0; ll < 24; ++ll) s += hl[(sq2 * 24 + ll) * HSTR + e2];
    cmean_s[idx] = s * (1.0f / 24.0f);
  }
  __syncthreads();
  if (active) {
    #pragma unroll
    for (int e = 0; e < 64; ++e) hl[r * HSTR + e] -= cmean_s[seq * 64 + e];
  }
  __syncthreads();
  // ---- dec head ----
  if (active) {
    int g = t >> 3;            // 0..23
    int u = g >> 1, half = g & 1;
    int sq = t & 7;
    const float* dwp = decw + u * 1536 + half * 768;
    int hbase = (sq * 24 + half * 12) * HSTR;
    float part = 0.f;
    for (int j = 0; j < 768; ++j) {
      int lr = j >> 6, d = j & 63;
      part += hl[hbase + lr * HSTR + d] * dwp[j];
    }
    pr_s[t] = part;
  }
  __syncthreads();
  if (t < 96) {
    int u = t >> 3, sq = t & 7;
    float v = pr_s[(u * 2) * 8 + sq] + pr_s[(u * 2 + 1) * 8 + sq] + decb[u];
    trelu[(size_t)(s0 + sq) * 12 + u] = fmaxf(v, 0.0f);
  }
}

// ---------------------------------------------------------------------------
// final combine
// ---------------------------------------------------------------------------
__global__ __launch_bounds__(64) void k_final(
    const float* __restrict__ x, const float* __restrict__ wx,
    const float* __restrict__ y1, const float* __restrict__ y2,
    const float* __restrict__ z1, const float* __restrict__ z2,
    const float* __restrict__ cs1, const float* __restrict__ cs2,
    const float* __restrict__ trelu,
    const float* __restrict__ alpha, const float* __restrict__ beta,
    const float* __restrict__ theta,
    const float* __restrict__ slinw, const float* __restrict__ slinb,
    const float* __restrict__ tlinw, const float* __restrict__ tlinb,
    float* __restrict__ out) {
  __shared__ float ly0[24], ly1[24], ly2[24], lz0[24], lz1[24], lz2[24];
  __shared__ float ltr[12], lsw[288];
  const int blk = blockIdx.x;
  const int b = blk >> 9, m = blk & 511;
  const int t = threadIdx.x;
  if (t < 24) {
    int row = (b * 24 + t) * 512 + m;
    ly0[t] = x[row];  ly1[t] = y1[row]; ly2[t] = y2[row];
    lz0[t] = wx[row]; lz1[t] = z1[row]; lz2[t] = z2[row];
  }
  if (t >= 48 && t < 60) ltr[t - 48] = trelu[(b * 512 + m) * 12 + (t - 48)];
  for (int i = t; i < 288; i += 64) lsw[i] = slinw[i];
  __syncthreads();
  const int o = t;
  const float at = alpha[0] + alpha[1] * cs1[m] + alpha[2] * cs2[m];
  const float b0 = beta[o], b1 = beta[64 + o], b2 = beta[128 + o];
  const float t0 = theta[o], t1 = theta[64 + o], t2 = theta[128 + o];
  float so[12];
  #pragma unroll
  for (int u = 0; u < 12; ++u) so[u] = 0.f;
  for (int tt = 0; tt < 24; ++tt) {
    float v = at + b0 * ly0[tt] + b1 * ly1[tt] + b2 * ly2[tt]
                 + t0 * lz0[tt] + t1 * lz1[tt] + t2 * lz2[tt];
    v = fmaxf(v, 0.0f);
    #pragma unroll
    for (int u = 0; u < 12; ++u) so[u] += lsw[u * 24 + tt] * v;
  }
  const float tw = tlinw[o], tb = tlinb[o];
  #pragma unroll
  for (int u = 0; u < 12; ++u) {
    float sval = so[u] + slinb[u];
    float tval = tw * ltr[u] + tb;
    float rr = fmaxf(sval * tval, 0.0f);
    out[(((size_t)b * 12 + u) * 512 + m) * 64 + o] = rr;
  }
}

// ===========================================================================
extern "C" void kernel_launch(void* const* d_in, const int* in_sizes, int n_in,
                              void* d_out, int out_size, void* d_ws, size_t ws_size,
                              hipStream_t stream) {
  (void)in_sizes; (void)n_in; (void)out_size; (void)ws_size;
  const float* s_w    = (const float*)d_in[0];
  const float* x      = (const float*)d_in[1];
  const float* swnn_w = (const float*)d_in[2];
  const float* swnn_b = (const float*)d_in[3];
  const float* alpha  = (const float*)d_in[4];
  const float* beta   = (const float*)d_in[5];
  const float* theta  = (const float*)d_in[6];
  const float* wq = (const float*)d_in[7];  const float* bq = (const float*)d_in[8];
  const float* wk = (const float*)d_in[9];  const float* bk = (const float*)d_in[10];
  const float* wv = (const float*)d_in[11]; const float* bv = (const float*)d_in[12];
  const float* wo = (const float*)d_in[13]; const float* bo = (const float*)d_in[14];
  const float* c1w = (const float*)d_in[15]; const float* c1b = (const float*)d_in[16];
  const float* c2w = (const float*)d_in[17]; const float* c2b = (const float*)d_in[18];
  const float* ng  = (const float*)d_in[19]; const float* nb  = (const float*)d_in[20];
  const float* decw = (const float*)d_in[21]; const float* decb = (const float*)d_in[22];
  const float* slinw = (const float*)d_in[23]; const float* slinb = (const float*)d_in[24];
  const float* tlinw = (const float*)d_in[25]; const float* tlinb = (const float*)d_in[26];
  (void)bq; (void)bk;

  float* wsf = (float*)d_ws;
  float* out = (float*)d_out;

  float* Wm = wsf + OFF_W;
  float* Sa = wsf + OFF_SA;
  float* Sb = wsf + OFF_SB;
  unsigned int* mbits = (unsigned int*)(wsf + OFF_SC) + 8;
  const float* scal = wsf + OFF_SC;

  k_prep<<<1, 256, 0, stream>>>(wsf);
  k_wprep<<<6, 256, 0, stream>>>(wq, wk, wv, wo, bv, bo, c1w, c2w, wsf);
  k_gemm_logits<<<dim3(16, 16), 256, 0, stream>>>(s_w, swnn_w, swnn_b, Wm);
  k_softmax_rows<<<512, 64, 0, stream>>>(Wm);

  // temporal branch
  k_temporal2<<<2048, 256, 0, stream>>>(x, wsf + OFF_PE, wsf + OFF_M, wsf + OFF_PT,
                                        wsf + OFF_C1T, wsf + OFF_C2T, wsf + OFF_BVO,
                                        c1b, c2b, ng, nb, decw, decb, wsf + OFF_TR);

  // eigen: scaling-squaring + power iteration
  k_init_S<<<1024, 256, 0, stream>>>(wsf);
  float* cur = Sa;
  float* nxt = Sb;
  for (int j = 0; j < EIG_K; ++j) {
    k_gemm_square<<<dim3(16, 16), 256, 0, stream>>>(cur, nxt, scal, mbits);
    k_bookkeep<<<1, 1, 0, stream>>>(wsf);
    float* tmp = cur; cur = nxt; nxt = tmp;
  }
  float* va = wsf + OFF_V0;
  float* vb = wsf + OFF_V1;
  for (int p = 0; p < MV_STEPS; ++p) {
    k_matvec<<<8, 64, 0, stream>>>(cur, va, vb, wsf, p);
    float* tmp = va; va = vb; vb = tmp;
  }
  k_lamfin<<<1, 1, 0, stream>>>(wsf);

  // spatial branch
  k_colsum<<<8, 64, 0, stream>>>(Wm, wsf);
  k_gemm_wx<<<dim3(16, 24), 256, 0, stream>>>(x, Wm, wsf + OFF_WX);
  k_gemm_yz<<<dim3(16, 24), 256, 0, stream>>>(x, wsf + OFF_WX, Wm, scal,
                                              wsf + OFF_Y1, wsf + OFF_Y2,
                                              wsf + OFF_Z1, wsf + OFF_Z2);
  k_final<<<16384, 64, 0, stream>>>(x, wsf + OFF_WX, wsf + OFF_Y1, wsf + OFF_Y2,
                                    wsf + OFF_Z1, wsf + OFF_Z2,
                                    wsf + OFF_CS1, wsf + OFF_CS2, wsf + OFF_TR,
                                    alpha, beta, theta, slinw, slinb,
                                    tlinw, tlinb, out);
}

// Round 8
// 2948.260 us; speedup vs baseline: 2.7003x; 1.5154x over previous
//
#include <hip/hip_runtime.h>
#include <hip/hip_bf16.h>
#include <math.h>

// ============================================================================
// GSTRGCT full forward.  N=512 B=32 T_IN=24 T_OUT=12 C_OUT=64 D=64 K=3
// LAYERS=2 DFF=256 MA=25 top_k=3. Output FLOAT32.
// ============================================================================

// ---------------- workspace layout (floats) ----------------
static const size_t OFF_W   = 0;
static const size_t OFF_SA  = OFF_W  + 512*512;
static const size_t OFF_SB  = OFF_SA + 512*512;
static const size_t OFF_WX  = OFF_SB + 512*512;
static const size_t OFF_Y1  = OFF_WX + 768*512;
static const size_t OFF_Y2  = OFF_Y1 + 768*512;
static const size_t OFF_Z1  = OFF_Y2 + 768*512;
static const size_t OFF_Z2  = OFF_Z1 + 768*512;
static const size_t OFF_TR  = OFF_Z2 + 768*512;       // 16384*12
static const size_t OFF_PE  = OFF_TR + 16384*12;      // 24*64
static const size_t OFF_CS1 = OFF_PE + 24*64;
static const size_t OFF_CS2 = OFF_CS1 + 512;
static const size_t OFF_V0  = OFF_CS2 + 512;
static const size_t OFF_V1  = OFF_V0 + 512;
static const size_t OFF_NA  = OFF_V1 + 512;           // 64
static const size_t OFF_SC  = OFF_NA + 64;            // 16 scalars
static const size_t OFF_M   = OFF_SC + 16;            // 64*64  Wq^T Wk
static const size_t OFF_PT  = OFF_M  + 4096;          // 64*64  (Wo Wv)^T as [d][e]
static const size_t OFF_C1T = OFF_PT + 4096;          // 64*256 c1w^T [d][f]
static const size_t OFF_C2T = OFF_C1T + 16384;        // 256*64 c2w^T [f][e]
static const size_t OFF_BVO = OFF_C2T + 16384;        // 64

#define EIG_H 0.125f
#define EIG_K 14        /* t = h*2^14 = 2048 (validated config, round 3) */
#define MV_STEPS 32

// ---------------------------------------------------------------------------
// prep: PE table, power-iter seed, normAcc zero
// ---------------------------------------------------------------------------
__global__ __launch_bounds__(256) void k_prep(float* __restrict__ wsf) {
  const int t = threadIdx.x;
  for (int idx = t; idx < 24 * 64; idx += 256) {
    int l = idx >> 6, d = idx & 63;
    int i = d >> 1;
    float div = expf((float)(2 * i) * (-9.210340371976184f / 64.0f));
    float ang = (float)l * div;
    wsf[OFF_PE + idx] = (d & 1) ? cosf(ang) : sinf(ang);
  }
  for (int idx = t; idx < 512; idx += 256)
    wsf[OFF_V0 + idx] = sinf((float)idx * 12.9898f + 0.5f) + 0.01f;
  for (int idx = t; idx < 64; idx += 256)
    wsf[OFF_NA + idx] = 0.0f;
}

// ---------------------------------------------------------------------------
// weight prep: M = Wq^T Wk ; PT[d][e] = (Wo Wv)[e][d] ; transposes ; bvo
// ---------------------------------------------------------------------------
__global__ __launch_bounds__(256) void k_wprep(
    const float* __restrict__ wq, const float* __restrict__ wk,
    const float* __restrict__ wv, const float* __restrict__ wo,
    const float* __restrict__ bv, const float* __restrict__ bo,
    const float* __restrict__ c1w, const float* __restrict__ c2w,
    float* __restrict__ wsf) {
  const int blk = blockIdx.x, t = threadIdx.x;
  if (blk == 0) {
    for (int i = 0; i < 16; ++i) {
      int idx = i * 256 + t;
      int d = idx >> 6, dp = idx & 63;
      float s = 0.f;
      for (int e = 0; e < 64; ++e) s += wq[e * 64 + d] * wk[e * 64 + dp];
      wsf[OFF_M + idx] = s;
    }
    if (t < 64) {
      float s = bo[t];
      for (int f = 0; f < 64; ++f) s += wo[t * 64 + f] * bv[f];
      wsf[OFF_BVO + t] = s;
    }
  } else if (blk == 1) {
    for (int i = 0; i < 16; ++i) {
      int idx = i * 256 + t;
      int d = idx >> 6, e = idx & 63;
      float s = 0.f;
      for (int f = 0; f < 64; ++f) s += wo[e * 64 + f] * wv[f * 64 + d];
      wsf[OFF_PT + idx] = s;
    }
  } else if (blk < 4) {
    int base = (blk - 2) * 8192;
    for (int i = 0; i < 32; ++i) {
      int idx = base + i * 256 + t;
      int d = idx >> 8, f = idx & 255;
      wsf[OFF_C1T + idx] = c1w[f * 64 + d];
    }
  } else {
    int base = (blk - 4) * 8192;
    for (int i = 0; i < 32; ++i) {
      int idx = base + i * 256 + t;
      int f = idx >> 6, e = idx & 63;
      wsf[OFF_C2T + idx] = c2w[e * 256 + f];
    }
  }
}

// ---------------------------------------------------------------------------
// logits = s_w @ swnn_w^T + swnn_b
// ---------------------------------------------------------------------------
__global__ __launch_bounds__(256) void k_gemm_logits(
    const float* __restrict__ A, const float* __restrict__ Bm,
    const float* __restrict__ bias, float* __restrict__ C) {
  __shared__ float As[32][33], Bs[32][33];
  const int tx = threadIdx.x & 31, ty = threadIdx.x >> 5;
  const int rb = blockIdx.y * 32, cb = blockIdx.x * 32;
  float acc[4] = {0.f, 0.f, 0.f, 0.f};
  for (int kk = 0; kk < 512; kk += 32) {
    for (int idx = threadIdx.x; idx < 1024; idx += 256) {
      int r = idx >> 5, c = idx & 31;
      As[r][c] = A[(rb + r) * 512 + kk + c];
      Bs[c][r] = Bm[(cb + r) * 512 + kk + c];
    }
    __syncthreads();
    for (int k2 = 0; k2 < 32; ++k2) {
      float bvv = Bs[k2][tx];
      #pragma unroll
      for (int i = 0; i < 4; ++i) acc[i] += As[ty + 8 * i][k2] * bvv;
    }
    __syncthreads();
  }
  float bb = bias[cb + tx];
  #pragma unroll
  for (int i = 0; i < 4; ++i)
    C[(rb + ty + 8 * i) * 512 + cb + tx] = acc[i] + bb;
}

__global__ __launch_bounds__(64) void k_softmax_rows(float* __restrict__ W) {
  const int r = blockIdx.x, t = threadIdx.x;
  float* row = W + (size_t)r * 512;
  float v[8];
  float mx = -3.4e38f;
  #pragma unroll
  for (int i = 0; i < 8; ++i) { v[i] = row[t + 64 * i]; mx = fmaxf(mx, v[i]); }
  for (int m = 1; m < 64; m <<= 1) mx = fmaxf(mx, __shfl_xor(mx, m));
  float s = 0.f;
  #pragma unroll
  for (int i = 0; i < 8; ++i) { v[i] = expf(v[i] - mx); s += v[i]; }
  for (int m = 1; m < 64; m <<= 1) s += __shfl_xor(s, m);
  float inv = 1.0f / s;
  #pragma unroll
  for (int i = 0; i < 8; ++i) row[t + 64 * i] = v[i] * inv;
}

__global__ __launch_bounds__(256) void k_init_S(float* __restrict__ wsf) {
  const int idx = blockIdx.x * 256 + threadIdx.x;
  const int i = idx >> 9, j = idx & 511;
  float w = wsf[OFF_W + idx];
  wsf[OFF_SA + idx] = ((i == j) ? 1.0f : 0.0f) - EIG_H * w;
  if (idx == 0) {
    wsf[OFF_SC + 0] = 0.0f;
    wsf[OFF_SC + 1] = 1.0f;
    ((unsigned int*)(wsf + OFF_SC))[8] = 0u;
  }
}

__global__ __launch_bounds__(256) void k_gemm_square(
    const float* __restrict__ A, float* __restrict__ C,
    const float* __restrict__ scal, unsigned int* __restrict__ mbits) {
  __shared__ float As[32][33], Bs[32][33];
  const int tx = threadIdx.x & 31, ty = threadIdx.x >> 5;
  const int rb = blockIdx.y * 32, cb = blockIdx.x * 32;
  float acc[4] = {0.f, 0.f, 0.f, 0.f};
  for (int kk = 0; kk < 512; kk += 32) {
    for (int idx = threadIdx.x; idx < 1024; idx += 256) {
      int r = idx >> 5, c = idx & 31;
      As[r][c] = A[(rb + r) * 512 + kk + c];
      Bs[r][c] = A[(kk + r) * 512 + cb + c];
    }
    __syncthreads();
    for (int k2 = 0; k2 < 32; ++k2) {
      float bvv = Bs[k2][tx];
      #pragma unroll
      for (int i = 0; i < 4; ++i) acc[i] += As[ty + 8 * i][k2] * bvv;
    }
    __syncthreads();
  }
  const float s = scal[1];
  const float s2 = s * s;
  float lmax = 0.f;
  #pragma unroll
  for (int i = 0; i < 4; ++i) {
    float v = acc[i] * s2;
    C[(rb + ty + 8 * i) * 512 + cb + tx] = v;
    lmax = fmaxf(lmax, fabsf(v));
  }
  for (int m = 1; m < 64; m <<= 1) lmax = fmaxf(lmax, __shfl_xor(lmax, m));
  if ((threadIdx.x & 63) == 0) atomicMax(mbits, __float_as_uint(lmax));
}

__global__ void k_bookkeep(float* __restrict__ wsf) {
  unsigned int* mb = (unsigned int*)(wsf + OFF_SC) + 8;
  float m = fmaxf(__uint_as_float(*mb), 1e-30f);
  wsf[OFF_SC + 0] = 2.0f * wsf[OFF_SC + 0] + logf(m);
  wsf[OFF_SC + 1] = 1.0f / m;
  *mb = 0u;
}

__global__ __launch_bounds__(64) void k_matvec(
    const float* __restrict__ S, const float* __restrict__ vin,
    float* __restrict__ vout, float* __restrict__ wsf, int p) {
  __shared__ float vv[512];
  const int t = threadIdx.x;
  const float invm = wsf[OFF_SC + 1];
  const float pn = (p == 0) ? 1.0f : fmaxf(wsf[OFF_NA + p - 1], 1e-30f);
  const float sc = invm / sqrtf(pn);
  for (int i = t; i < 512; i += 64) vv[i] = vin[i];
  __syncthreads();
  const int row = blockIdx.x * 64 + t;
  const float* rp = S + (size_t)row * 512;
  float acc = 0.f;
  for (int j = 0; j < 512; j += 4) {
    float4 a = *(const float4*)(rp + j);
    acc += a.x * vv[j] + a.y * vv[j + 1] + a.z * vv[j + 2] + a.w * vv[j + 3];
  }
  float y = acc * sc;
  vout[row] = y;
  float ss = y * y;
  for (int m = 1; m < 64; m <<= 1) ss += __shfl_xor(ss, m);
  if (t == 0) atomicAdd(&wsf[OFF_NA + p], ss);
}

__global__ void k_lamfin(float* __restrict__ wsf) {
  float slope = 0.f;
  for (int p = 8; p < 32; ++p) slope += 0.5f * logf(fmaxf(wsf[OFF_NA + p], 1e-30f));
  slope *= (1.0f / 24.0f);
  float rate = (slope + wsf[OFF_SC + 0]) * (1.0f / 16384.0f);
  float minre = (1.0f - expf(rate)) * (1.0f / EIG_H);
  float lam = 1.0f - minre;
  wsf[OFF_SC + 2] = lam;
  wsf[OFF_SC + 3] = 2.0f / lam - 1.0f;
  wsf[OFF_SC + 4] = 2.0f / lam;
}

__global__ __launch_bounds__(64) void k_colsum(const float* __restrict__ W,
                                               float* __restrict__ wsf) {
  const int m = blockIdx.x * 64 + threadIdx.x;
  float s1 = 0.f, s2 = 0.f;
  for (int n = 0; n < 512; ++n) {
    float w = W[n * 512 + m];
    s1 += w; s2 += w * w;
  }
  float wmm = W[m * 512 + m];
  float a = wsf[OFF_SC + 3], c = wsf[OFF_SC + 4];
  wsf[OFF_CS1 + m] = a - c * s1;
  wsf[OFF_CS2 + m] = 2.0f * (c * c * s2 + a * a - 2.0f * a * c * wmm) - 1.0f;
}

__global__ __launch_bounds__(256) void k_gemm_wx(
    const float* __restrict__ A, const float* __restrict__ Bm,
    float* __restrict__ C) {
  __shared__ float As[32][33], Bs[32][33];
  const int tx = threadIdx.x & 31, ty = threadIdx.x >> 5;
  const int rb = blockIdx.y * 32, cb = blockIdx.x * 32;
  float acc[4] = {0.f, 0.f, 0.f, 0.f};
  for (int kk = 0; kk < 512; kk += 32) {
    for (int idx = threadIdx.x; idx < 1024; idx += 256) {
      int r = idx >> 5, c = idx & 31;
      As[r][c] = A[(rb + r) * 512 + kk + c];
      Bs[r][c] = Bm[(kk + r) * 512 + cb + c];
    }
    __syncthreads();
    for (int k2 = 0; k2 < 32; ++k2) {
      float bvv = Bs[k2][tx];
      #pragma unroll
      for (int i = 0; i < 4; ++i) acc[i] += As[ty + 8 * i][k2] * bvv;
    }
    __syncthreads();
  }
  #pragma unroll
  for (int i = 0; i < 4; ++i)
    C[(rb + ty + 8 * i) * 512 + cb + tx] = acc[i];
}

__global__ __launch_bounds__(256) void k_gemm_yz(
    const float* __restrict__ X, const float* __restrict__ WX,
    const float* __restrict__ W, const float* __restrict__ sc,
    float* __restrict__ y1, float* __restrict__ y2,
    float* __restrict__ z1, float* __restrict__ z2) {
  __shared__ float Xs[32][33], Ms[32][33], C1s[32][33], C2s[32][33];
  const int tx = threadIdx.x & 31, ty = threadIdx.x >> 5;
  const int rb = blockIdx.y * 32, cb = blockIdx.x * 32;
  const float a = sc[3], c = sc[4];
  float ay1[4] = {0,0,0,0}, ay2[4] = {0,0,0,0}, az1[4] = {0,0,0,0}, az2[4] = {0,0,0,0};
  for (int kk = 0; kk < 512; kk += 32) {
    for (int idx = threadIdx.x; idx < 1024; idx += 256) {
      int r = idx >> 5, cc = idx & 31;
      Xs[r][cc] = X[(rb + r) * 512 + kk + cc];
      Ms[r][cc] = WX[(rb + r) * 512 + kk + cc];
      float w = W[(kk + r) * 512 + cb + cc];
      float dl = ((kk + r) == (cb + cc)) ? 1.0f : 0.0f;
      float c1 = a * dl - c * w;
      C1s[r][cc] = c1;
      C2s[r][cc] = 2.0f * c1 * c1 - dl;
    }
    __syncthreads();
    for (int k2 = 0; k2 < 32; ++k2) {
      float b1 = C1s[k2][tx], b2 = C2s[k2][tx];
      #pragma unroll
      for (int i = 0; i < 4; ++i) {
        float xv = Xs[ty + 8 * i][k2];
        float wv = Ms[ty + 8 * i][k2];
        ay1[i] += xv * b1; ay2[i] += xv * b2;
        az1[i] += wv * b1; az2[i] += wv * b2;
      }
    }
    __syncthreads();
  }
  #pragma unroll
  for (int i = 0; i < 4; ++i) {
    int off = (rb + ty + 8 * i) * 512 + cb + tx;
    y1[off] = ay1[i]; y2[off] = ay2[i];
    z1[off] = az1[i]; z2[off] = az2[i];
  }
}

// ---------------------------------------------------------------------------
// temporal branch v4: 8 seqs/block, thread-per-row, uniform-address weights,
// full fp32, register-pressure-capped (~90 live):
//  - delay+P fused (no agg[64] array)
//  - FF f-chunked by 16 (y16[16] + a2[64])
//  - decomp column-chunked 2x32 (ma[32] across barrier)
//  - LN via 3 LDS passes (no hr[64])
// LDS ~53.7 KB -> 2 blocks/CU.
// ---------------------------------------------------------------------------
#define HSTR 65

__device__ __forceinline__ void decomp_block(float* hl, int r, int seq, int l,
                                             bool active) {
  #pragma unroll
  for (int ch = 0; ch < 2; ++ch) {
    float ma[32];
    if (active) {
      #pragma unroll
      for (int dc = 0; dc < 8; ++dc) {
        float s0 = 0.f, s1 = 0.f, s2 = 0.f, s3 = 0.f;
        for (int j = 0; j < 25; ++j) {
          int jj = l - 12 + j;
          jj = jj < 0 ? 0 : (jj > 23 ? 23 : jj);
          int bb = (seq * 24 + jj) * HSTR + ch * 32 + dc * 4;
          s0 += hl[bb]; s1 += hl[bb + 1]; s2 += hl[bb + 2]; s3 += hl[bb + 3];
        }
        ma[dc * 4] = s0; ma[dc * 4 + 1] = s1; ma[dc * 4 + 2] = s2; ma[dc * 4 + 3] = s3;
      }
    }
    __syncthreads();
    if (active) {
      #pragma unroll
      for (int e = 0; e < 32; ++e)
        hl[r * HSTR + ch * 32 + e] -= ma[e] * (1.0f / 25.0f);
    }
    if (ch == 0) { /* chunk-1 writes (cols 0..31) disjoint from chunk-2 reads (cols 32..63) */ }
    else __syncthreads();
  }
}

__global__ __launch_bounds__(256, 2) void k_temporal2(
    const float* __restrict__ x, const float* __restrict__ pe,
    const float* __restrict__ Mw, const float* __restrict__ PTw,
    const float* __restrict__ C1T, const float* __restrict__ C2T,
    const float* __restrict__ bvo,
    const float* __restrict__ c1b, const float* __restrict__ c2b,
    const float* __restrict__ ng, const float* __restrict__ nbv,
    const float* __restrict__ decw, const float* __restrict__ decb,
    float* __restrict__ trelu) {
  __shared__ float hl[8 * 24 * HSTR];        // 49920 B
  __shared__ float corr_s[192];
  __shared__ float cmean_s[512];
  __shared__ float wsm_s[24];
  __shared__ int dly_s[24];
  __shared__ float pr_s[192];

  const int t = threadIdx.x;
  const int s0 = blockIdx.x * 8;
  const bool active = t < 192;
  const int r = t;
  const int seq = r / 24;
  const int l = r - seq * 24;
  const int gseq = s0 + seq;
  const int b = gseq >> 9, n = gseq & 511;

  // ---- init h = x + pe ----
  if (active) {
    float xv = x[(b * 24 + l) * 512 + n];
    const float4* per = (const float4*)(pe + l * 64);
    #pragma unroll
    for (int c = 0; c < 16; ++c) {
      float4 pv = per[c];
      int bb = r * HSTR + c * 4;
      hl[bb] = xv + pv.x; hl[bb + 1] = xv + pv.y;
      hl[bb + 2] = xv + pv.z; hl[bb + 3] = xv + pv.w;
    }
  }
  __syncthreads();

  for (int layer = 0; layer < 2; ++layer) {
    // ---- zero corr ----
    if (active) corr_s[t] = 0.f;
    __syncthreads();
    // ---- u = M^T h (own row), then corr partials ----
    {
      float u[64];
      #pragma unroll
      for (int e = 0; e < 64; ++e) u[e] = 0.f;
      if (active) {
        for (int d = 0; d < 64; ++d) {
          float hv = hl[r * HSTR + d];
          const float* Mr = Mw + d * 64;
          #pragma unroll
          for (int e = 0; e < 64; ++e) u[e] += hv * Mr[e];
        }
        for (int tau = 0; tau < 24; ++tau) {
          int l2 = l - tau; if (l2 < 0) l2 += 24;
          int bb = (seq * 24 + l2) * HSTR;
          float acc = 0.f;
          #pragma unroll
          for (int d = 0; d < 64; ++d) acc += u[d] * hl[bb + d];
          atomicAdd(&corr_s[seq * 24 + tau], acc * (1.0f / 64.0f));
        }
      }
    }
    __syncthreads();
    // ---- top-3 + softmax (per seq) ----
    if (t < 8) {
      const float* cr = corr_s + t * 24;
      int i0 = 0, i1 = 0, i2 = 0;
      float v0 = -3.4e38f, v1 = -3.4e38f, v2 = -3.4e38f;
      for (int j = 0; j < 24; ++j) { float v = cr[j]; if (v > v0) { v0 = v; i0 = j; } }
      for (int j = 0; j < 24; ++j) { if (j == i0) continue; float v = cr[j]; if (v > v1) { v1 = v; i1 = j; } }
      for (int j = 0; j < 24; ++j) { if (j == i0 || j == i1) continue; float v = cr[j]; if (v > v2) { v2 = v; i2 = j; } }
      float e1 = expf(v1 - v0), e2 = expf(v2 - v0);
      float inv = 1.0f / (1.0f + e1 + e2);
      wsm_s[t * 3] = inv; wsm_s[t * 3 + 1] = e1 * inv; wsm_s[t * 3 + 2] = e2 * inv;
      dly_s[t * 3] = i0; dly_s[t * 3 + 1] = i1; dly_s[t * 3 + 2] = i2;
    }
    __syncthreads();
    // ---- fused delay-agg + P matvec: acc = P (w0 h_l0 + w1 h_l1 + w2 h_l2) ----
    {
      float acc[64];
      #pragma unroll
      for (int e = 0; e < 64; ++e) acc[e] = 0.f;
      if (active) {
        float w0 = wsm_s[seq * 3], w1 = wsm_s[seq * 3 + 1], w2 = wsm_s[seq * 3 + 2];
        int d0 = dly_s[seq * 3], d1 = dly_s[seq * 3 + 1], d2 = dly_s[seq * 3 + 2];
        int l0 = l + d0; if (l0 >= 24) l0 -= 24;
        int l1 = l + d1; if (l1 >= 24) l1 -= 24;
        int l2 = l + d2; if (l2 >= 24) l2 -= 24;
        int b0 = (seq * 24 + l0) * HSTR, b1 = (seq * 24 + l1) * HSTR, b2 = (seq * 24 + l2) * HSTR;
        for (int d = 0; d < 64; ++d) {
          float aggd = w0 * hl[b0 + d] + w1 * hl[b1 + d] + w2 * hl[b2 + d];
          const float* Pr = PTw + d * 64;
          #pragma unroll
          for (int e = 0; e < 64; ++e) acc[e] += aggd * Pr[e];
        }
      }
      __syncthreads();   // all hl reads complete before any writes
      if (active) {
        #pragma unroll
        for (int e = 0; e < 64; ++e) hl[r * HSTR + e] += acc[e] + bvo[e];
      }
    }
    __syncthreads();
    decomp_block(hl, r, seq, l, active);
    // ---- fused FF: conv1(relu) -> conv2, f-chunked by 16 ----
    {
      float a2[64];
      #pragma unroll
      for (int e = 0; e < 64; ++e) a2[e] = 0.f;
      if (active) {
        for (int fc = 0; fc < 16; ++fc) {
          float y16[16];
          #pragma unroll
          for (int f = 0; f < 16; ++f) y16[f] = 0.f;
          for (int d = 0; d < 64; ++d) {
            float hv = hl[r * HSTR + d];
            const float* c1r = C1T + d * 256 + fc * 16;
            #pragma unroll
            for (int f = 0; f < 16; ++f) y16[f] += hv * c1r[f];
          }
          #pragma unroll
          for (int f = 0; f < 16; ++f)
            y16[f] = fmaxf(y16[f] + c1b[fc * 16 + f], 0.0f);
          #pragma unroll
          for (int f = 0; f < 16; ++f) {
            float yf = y16[f];
            const float* r2 = C2T + (fc * 16 + f) * 64;
            #pragma unroll
            for (int e = 0; e < 64; ++e) a2[e] += yf * r2[e];
          }
        }
        #pragma unroll
        for (int e = 0; e < 64; ++e) hl[r * HSTR + e] += a2[e] + c2b[e];
      }
    }
    __syncthreads();
    decomp_block(hl, r, seq, l, active);
  }

  // ---- LayerNorm over D (3 LDS passes, no big register array) ----
  if (active) {
    float mu = 0.f;
    #pragma unroll
    for (int e = 0; e < 64; ++e) mu += hl[r * HSTR + e];
    mu *= (1.0f / 64.0f);
    float vs = 0.f;
    #pragma unroll
    for (int e = 0; e < 64; ++e) { float d = hl[r * HSTR + e] - mu; vs += d * d; }
    float rs = rsqrtf(vs * (1.0f / 64.0f) + 1e-5f);
    #pragma unroll
    for (int e = 0; e < 64; ++e)
      hl[r * HSTR + e] = (hl[r * HSTR + e] - mu) * rs * ng[e] + nbv[e];
  }
  __syncthreads();
  // ---- my_Layernorm: subtract column mean over L ----
  for (int pass = 0; pass < 2; ++pass) {
    int idx = pass * 256 + t;
    int sq2 = idx >> 6, e2 = idx & 63;
    float s = 0.f;
    for (int ll = 0; ll < 24; ++ll) s += hl[(sq2 * 24 + ll) * HSTR + e2];
    cmean_s[idx] = s * (1.0f / 24.0f);
  }
  __syncthreads();
  if (active) {
    #pragma unroll
    for (int e = 0; e < 64; ++e) hl[r * HSTR + e] -= cmean_s[seq * 64 + e];
  }
  __syncthreads();
  // ---- dec head ----
  if (active) {
    int g = t >> 3;            // 0..23
    int u = g >> 1, half = g & 1;
    int sq = t & 7;
    const float* dwp = decw + u * 1536 + half * 768;
    int hbase = (sq * 24 + half * 12) * HSTR;
    float part = 0.f;
    for (int j = 0; j < 768; ++j) {
      int lr = j >> 6, d = j & 63;
      part += hl[hbase + lr * HSTR + d] * dwp[j];
    }
    pr_s[t] = part;
  }
  __syncthreads();
  if (t < 96) {
    int u = t >> 3, sq = t & 7;
    float v = pr_s[(u * 2) * 8 + sq] + pr_s[(u * 2 + 1) * 8 + sq] + decb[u];
    trelu[(size_t)(s0 + sq) * 12 + u] = fmaxf(v, 0.0f);
  }
}

// ---------------------------------------------------------------------------
// final combine
// ---------------------------------------------------------------------------
__global__ __launch_bounds__(64) void k_final(
    const float* __restrict__ x, const float* __restrict__ wx,
    const float* __restrict__ y1, const float* __restrict__ y2,
    const float* __restrict__ z1, const float* __restrict__ z2,
    const float* __restrict__ cs1, const float* __restrict__ cs2,
    const float* __restrict__ trelu,
    const float* __restrict__ alpha, const float* __restrict__ beta,
    const float* __restrict__ theta,
    const float* __restrict__ slinw, const float* __restrict__ slinb,
    const float* __restrict__ tlinw, const float* __restrict__ tlinb,
    float* __restrict__ out) {
  __shared__ float ly0[24], ly1[24], ly2[24], lz0[24], lz1[24], lz2[24];
  __shared__ float ltr[12], lsw[288];
  const int blk = blockIdx.x;
  const int b = blk >> 9, m = blk & 511;
  const int t = threadIdx.x;
  if (t < 24) {
    int row = (b * 24 + t) * 512 + m;
    ly0[t] = x[row];  ly1[t] = y1[row]; ly2[t] = y2[row];
    lz0[t] = wx[row]; lz1[t] = z1[row]; lz2[t] = z2[row];
  }
  if (t >= 48 && t < 60) ltr[t - 48] = trelu[(b * 512 + m) * 12 + (t - 48)];
  for (int i = t; i < 288; i += 64) lsw[i] = slinw[i];
  __syncthreads();
  const int o = t;
  const float at = alpha[0] + alpha[1] * cs1[m] + alpha[2] * cs2[m];
  const float b0 = beta[o], b1 = beta[64 + o], b2 = beta[128 + o];
  const float t0 = theta[o], t1 = theta[64 + o], t2 = theta[128 + o];
  float so[12];
  #pragma unroll
  for (int u = 0; u < 12; ++u) so[u] = 0.f;
  for (int tt = 0; tt < 24; ++tt) {
    float v = at + b0 * ly0[tt] + b1 * ly1[tt] + b2 * ly2[tt]
                 + t0 * lz0[tt] + t1 * lz1[tt] + t2 * lz2[tt];
    v = fmaxf(v, 0.0f);
    #pragma unroll
    for (int u = 0; u < 12; ++u) so[u] += lsw[u * 24 + tt] * v;
  }
  const float tw = tlinw[o], tb = tlinb[o];
  #pragma unroll
  for (int u = 0; u < 12; ++u) {
    float sval = so[u] + slinb[u];
    float tval = tw * ltr[u] + tb;
    float rr = fmaxf(sval * tval, 0.0f);
    out[(((size_t)b * 12 + u) * 512 + m) * 64 + o] = rr;
  }
}

// ===========================================================================
extern "C" void kernel_launch(void* const* d_in, const int* in_sizes, int n_in,
                              void* d_out, int out_size, void* d_ws, size_t ws_size,
                              hipStream_t stream) {
  (void)in_sizes; (void)n_in; (void)out_size; (void)ws_size;
  const float* s_w    = (const float*)d_in[0];
  const float* x      = (const float*)d_in[1];
  const float* swnn_w = (const float*)d_in[2];
  const float* swnn_b = (const float*)d_in[3];
  const float* alpha  = (const float*)d_in[4];
  const float* beta   = (const float*)d_in[5];
  const float* theta  = (const float*)d_in[6];
  const float* wq = (const float*)d_in[7];  const float* bq = (const float*)d_in[8];
  const float* wk = (const float*)d_in[9];  const float* bk = (const float*)d_in[10];
  const float* wv = (const float*)d_in[11]; const float* bv = (const float*)d_in[12];
  const float* wo = (const float*)d_in[13]; const float* bo = (const float*)d_in[14];
  const float* c1w = (const float*)d_in[15]; const float* c1b = (const float*)d_in[16];
  const float* c2w = (const float*)d_in[17]; const float* c2b = (const float*)d_in[18];
  const float* ng  = (const float*)d_in[19]; const float* nb  = (const float*)d_in[20];
  const float* decw = (const float*)d_in[21]; const float* decb = (const float*)d_in[22];
  const float* slinw = (const float*)d_in[23]; const float* slinb = (const float*)d_in[24];
  const float* tlinw = (const float*)d_in[25]; const float* tlinb = (const float*)d_in[26];
  (void)bq; (void)bk;

  float* wsf = (float*)d_ws;
  float* out = (float*)d_out;

  float* Wm = wsf + OFF_W;
  float* Sa = wsf + OFF_SA;
  float* Sb = wsf + OFF_SB;
  unsigned int* mbits = (unsigned int*)(wsf + OFF_SC) + 8;
  const float* scal = wsf + OFF_SC;

  k_prep<<<1, 256, 0, stream>>>(wsf);
  k_wprep<<<6, 256, 0, stream>>>(wq, wk, wv, wo, bv, bo, c1w, c2w, wsf);
  k_gemm_logits<<<dim3(16, 16), 256, 0, stream>>>(s_w, swnn_w, swnn_b, Wm);
  k_softmax_rows<<<512, 64, 0, stream>>>(Wm);

  // temporal branch
  k_temporal2<<<2048, 256, 0, stream>>>(x, wsf + OFF_PE, wsf + OFF_M, wsf + OFF_PT,
                                        wsf + OFF_C1T, wsf + OFF_C2T, wsf + OFF_BVO,
                                        c1b, c2b, ng, nb, decw, decb, wsf + OFF_TR);

  // eigen: scaling-squaring + power iteration
  k_init_S<<<1024, 256, 0, stream>>>(wsf);
  float* cur = Sa;
  float* nxt = Sb;
  for (int j = 0; j < EIG_K; ++j) {
    k_gemm_square<<<dim3(16, 16), 256, 0, stream>>>(cur, nxt, scal, mbits);
    k_bookkeep<<<1, 1, 0, stream>>>(wsf);
    float* tmp = cur; cur = nxt; nxt = tmp;
  }
  float* va = wsf + OFF_V0;
  float* vb = wsf + OFF_V1;
  for (int p = 0; p < MV_STEPS; ++p) {
    k_matvec<<<8, 64, 0, stream>>>(cur, va, vb, wsf, p);
    float* tmp = va; va = vb; vb = tmp;
  }
  k_lamfin<<<1, 1, 0, stream>>>(wsf);

  // spatial branch
  k_colsum<<<8, 64, 0, stream>>>(Wm, wsf);
  k_gemm_wx<<<dim3(16, 24), 256, 0, stream>>>(x, Wm, wsf + OFF_WX);
  k_gemm_yz<<<dim3(16, 24), 256, 0, stream>>>(x, wsf + OFF_WX, Wm, scal,
                                              wsf + OFF_Y1, wsf + OFF_Y2,
                                              wsf + OFF_Z1, wsf + OFF_Z2);
  k_final<<<16384, 64, 0, stream>>>(x, wsf + OFF_WX, wsf + OFF_Y1, wsf + OFF_Y2,
                                    wsf + OFF_Z1, wsf + OFF_Z2,
                                    wsf + OFF_CS1, wsf + OFF_CS2, wsf + OFF_TR,
                                    alpha, beta, theta, slinw, slinb,
                                    tlinw, tlinb, out);
}

// Round 9
// 2887.767 us; speedup vs baseline: 2.7568x; 1.0209x over previous
//
#include <hip/hip_runtime.h>
#include <hip/hip_bf16.h>
#include <math.h>

// ============================================================================
// GSTRGCT full forward.  N=512 B=32 T_IN=24 T_OUT=12 C_OUT=64 D=64 K=3
// LAYERS=2 DFF=256 MA=25 top_k=3. Output FLOAT32.
// ============================================================================

// ---------------- workspace layout (floats) ----------------
static const size_t OFF_W   = 0;
static const size_t OFF_SA  = OFF_W  + 512*512;
static const size_t OFF_SB  = OFF_SA + 512*512;
static const size_t OFF_WX  = OFF_SB + 512*512;
static const size_t OFF_Y1  = OFF_WX + 768*512;
static const size_t OFF_Y2  = OFF_Y1 + 768*512;
static const size_t OFF_Z1  = OFF_Y2 + 768*512;
static const size_t OFF_Z2  = OFF_Z1 + 768*512;
static const size_t OFF_TR  = OFF_Z2 + 768*512;       // 16384*12
static const size_t OFF_PE  = OFF_TR + 16384*12;      // 24*64
static const size_t OFF_CS1 = OFF_PE + 24*64;
static const size_t OFF_CS2 = OFF_CS1 + 512;
static const size_t OFF_V0  = OFF_CS2 + 512;
static const size_t OFF_V1  = OFF_V0 + 512;
static const size_t OFF_NA  = OFF_V1 + 512;           // 64
static const size_t OFF_SC  = OFF_NA + 64;            // 16 scalars
static const size_t OFF_M   = OFF_SC + 16;            // 64*64  Wq^T Wk
static const size_t OFF_PT  = OFF_M  + 4096;          // 64*64  (Wo Wv)^T as [d][e]
static const size_t OFF_C1T = OFF_PT + 4096;          // 64*256 c1w^T [d][f]
static const size_t OFF_C2T = OFF_C1T + 16384;        // 256*64 c2w^T [f][e]
static const size_t OFF_BVO = OFF_C2T + 16384;        // 64

#define EIG_H 0.125f
#define EIG_K 14        /* t = h*2^14 = 2048 (validated config, round 3) */
#define MV_STEPS 32

// ---------------------------------------------------------------------------
// prep: PE table, power-iter seed, normAcc zero
// ---------------------------------------------------------------------------
__global__ __launch_bounds__(256) void k_prep(float* __restrict__ wsf) {
  const int t = threadIdx.x;
  for (int idx = t; idx < 24 * 64; idx += 256) {
    int l = idx >> 6, d = idx & 63;
    int i = d >> 1;
    float div = expf((float)(2 * i) * (-9.210340371976184f / 64.0f));
    float ang = (float)l * div;
    wsf[OFF_PE + idx] = (d & 1) ? cosf(ang) : sinf(ang);
  }
  for (int idx = t; idx < 512; idx += 256)
    wsf[OFF_V0 + idx] = sinf((float)idx * 12.9898f + 0.5f) + 0.01f;
  for (int idx = t; idx < 64; idx += 256)
    wsf[OFF_NA + idx] = 0.0f;
}

// ---------------------------------------------------------------------------
// weight prep: M = Wq^T Wk ; PT[d][e] = (Wo Wv)[e][d] ; transposes ; bvo
// ---------------------------------------------------------------------------
__global__ __launch_bounds__(256) void k_wprep(
    const float* __restrict__ wq, const float* __restrict__ wk,
    const float* __restrict__ wv, const float* __restrict__ wo,
    const float* __restrict__ bv, const float* __restrict__ bo,
    const float* __restrict__ c1w, const float* __restrict__ c2w,
    float* __restrict__ wsf) {
  const int blk = blockIdx.x, t = threadIdx.x;
  if (blk == 0) {
    for (int i = 0; i < 16; ++i) {
      int idx = i * 256 + t;
      int d = idx >> 6, dp = idx & 63;
      float s = 0.f;
      for (int e = 0; e < 64; ++e) s += wq[e * 64 + d] * wk[e * 64 + dp];
      wsf[OFF_M + idx] = s;
    }
    if (t < 64) {
      float s = bo[t];
      for (int f = 0; f < 64; ++f) s += wo[t * 64 + f] * bv[f];
      wsf[OFF_BVO + t] = s;
    }
  } else if (blk == 1) {
    for (int i = 0; i < 16; ++i) {
      int idx = i * 256 + t;
      int d = idx >> 6, e = idx & 63;
      float s = 0.f;
      for (int f = 0; f < 64; ++f) s += wo[e * 64 + f] * wv[f * 64 + d];
      wsf[OFF_PT + idx] = s;
    }
  } else if (blk < 4) {
    int base = (blk - 2) * 8192;
    for (int i = 0; i < 32; ++i) {
      int idx = base + i * 256 + t;
      int d = idx >> 8, f = idx & 255;
      wsf[OFF_C1T + idx] = c1w[f * 64 + d];
    }
  } else {
    int base = (blk - 4) * 8192;
    for (int i = 0; i < 32; ++i) {
      int idx = base + i * 256 + t;
      int f = idx >> 6, e = idx & 63;
      wsf[OFF_C2T + idx] = c2w[e * 256 + f];
    }
  }
}

// ---------------------------------------------------------------------------
// logits = s_w @ swnn_w^T + swnn_b
// ---------------------------------------------------------------------------
__global__ __launch_bounds__(256) void k_gemm_logits(
    const float* __restrict__ A, const float* __restrict__ Bm,
    const float* __restrict__ bias, float* __restrict__ C) {
  __shared__ float As[32][33], Bs[32][33];
  const int tx = threadIdx.x & 31, ty = threadIdx.x >> 5;
  const int rb = blockIdx.y * 32, cb = blockIdx.x * 32;
  float acc[4] = {0.f, 0.f, 0.f, 0.f};
  for (int kk = 0; kk < 512; kk += 32) {
    for (int idx = threadIdx.x; idx < 1024; idx += 256) {
      int r = idx >> 5, c = idx & 31;
      As[r][c] = A[(rb + r) * 512 + kk + c];
      Bs[c][r] = Bm[(cb + r) * 512 + kk + c];
    }
    __syncthreads();
    for (int k2 = 0; k2 < 32; ++k2) {
      float bvv = Bs[k2][tx];
      #pragma unroll
      for (int i = 0; i < 4; ++i) acc[i] += As[ty + 8 * i][k2] * bvv;
    }
    __syncthreads();
  }
  float bb = bias[cb + tx];
  #pragma unroll
  for (int i = 0; i < 4; ++i)
    C[(rb + ty + 8 * i) * 512 + cb + tx] = acc[i] + bb;
}

__global__ __launch_bounds__(64) void k_softmax_rows(float* __restrict__ W) {
  const int r = blockIdx.x, t = threadIdx.x;
  float* row = W + (size_t)r * 512;
  float v[8];
  float mx = -3.4e38f;
  #pragma unroll
  for (int i = 0; i < 8; ++i) { v[i] = row[t + 64 * i]; mx = fmaxf(mx, v[i]); }
  for (int m = 1; m < 64; m <<= 1) mx = fmaxf(mx, __shfl_xor(mx, m));
  float s = 0.f;
  #pragma unroll
  for (int i = 0; i < 8; ++i) { v[i] = expf(v[i] - mx); s += v[i]; }
  for (int m = 1; m < 64; m <<= 1) s += __shfl_xor(s, m);
  float inv = 1.0f / s;
  #pragma unroll
  for (int i = 0; i < 8; ++i) row[t + 64 * i] = v[i] * inv;
}

__global__ __launch_bounds__(256) void k_init_S(float* __restrict__ wsf) {
  const int idx = blockIdx.x * 256 + threadIdx.x;
  const int i = idx >> 9, j = idx & 511;
  float w = wsf[OFF_W + idx];
  wsf[OFF_SA + idx] = ((i == j) ? 1.0f : 0.0f) - EIG_H * w;
  if (idx == 0) {
    wsf[OFF_SC + 0] = 0.0f;
    wsf[OFF_SC + 1] = 1.0f;
    ((unsigned int*)(wsf + OFF_SC))[8] = 0u;
  }
}

__global__ __launch_bounds__(256) void k_gemm_square(
    const float* __restrict__ A, float* __restrict__ C,
    const float* __restrict__ scal, unsigned int* __restrict__ mbits) {
  __shared__ float As[32][33], Bs[32][33];
  const int tx = threadIdx.x & 31, ty = threadIdx.x >> 5;
  const int rb = blockIdx.y * 32, cb = blockIdx.x * 32;
  float acc[4] = {0.f, 0.f, 0.f, 0.f};
  for (int kk = 0; kk < 512; kk += 32) {
    for (int idx = threadIdx.x; idx < 1024; idx += 256) {
      int r = idx >> 5, c = idx & 31;
      As[r][c] = A[(rb + r) * 512 + kk + c];
      Bs[r][c] = A[(kk + r) * 512 + cb + c];
    }
    __syncthreads();
    for (int k2 = 0; k2 < 32; ++k2) {
      float bvv = Bs[k2][tx];
      #pragma unroll
      for (int i = 0; i < 4; ++i) acc[i] += As[ty + 8 * i][k2] * bvv;
    }
    __syncthreads();
  }
  const float s = scal[1];
  const float s2 = s * s;
  float lmax = 0.f;
  #pragma unroll
  for (int i = 0; i < 4; ++i) {
    float v = acc[i] * s2;
    C[(rb + ty + 8 * i) * 512 + cb + tx] = v;
    lmax = fmaxf(lmax, fabsf(v));
  }
  for (int m = 1; m < 64; m <<= 1) lmax = fmaxf(lmax, __shfl_xor(lmax, m));
  if ((threadIdx.x & 63) == 0) atomicMax(mbits, __float_as_uint(lmax));
}

__global__ void k_bookkeep(float* __restrict__ wsf) {
  unsigned int* mb = (unsigned int*)(wsf + OFF_SC) + 8;
  float m = fmaxf(__uint_as_float(*mb), 1e-30f);
  wsf[OFF_SC + 0] = 2.0f * wsf[OFF_SC + 0] + logf(m);
  wsf[OFF_SC + 1] = 1.0f / m;
  *mb = 0u;
}

__global__ __launch_bounds__(64) void k_matvec(
    const float* __restrict__ S, const float* __restrict__ vin,
    float* __restrict__ vout, float* __restrict__ wsf, int p) {
  __shared__ float vv[512];
  const int t = threadIdx.x;
  const float invm = wsf[OFF_SC + 1];
  const float pn = (p == 0) ? 1.0f : fmaxf(wsf[OFF_NA + p - 1], 1e-30f);
  const float sc = invm / sqrtf(pn);
  for (int i = t; i < 512; i += 64) vv[i] = vin[i];
  __syncthreads();
  const int row = blockIdx.x * 64 + t;
  const float* rp = S + (size_t)row * 512;
  float acc = 0.f;
  for (int j = 0; j < 512; j += 4) {
    float4 a = *(const float4*)(rp + j);
    acc += a.x * vv[j] + a.y * vv[j + 1] + a.z * vv[j + 2] + a.w * vv[j + 3];
  }
  float y = acc * sc;
  vout[row] = y;
  float ss = y * y;
  for (int m = 1; m < 64; m <<= 1) ss += __shfl_xor(ss, m);
  if (t == 0) atomicAdd(&wsf[OFF_NA + p], ss);
}

__global__ void k_lamfin(float* __restrict__ wsf) {
  float slope = 0.f;
  for (int p = 8; p < 32; ++p) slope += 0.5f * logf(fmaxf(wsf[OFF_NA + p], 1e-30f));
  slope *= (1.0f / 24.0f);
  float rate = (slope + wsf[OFF_SC + 0]) * (1.0f / 16384.0f);
  float minre = (1.0f - expf(rate)) * (1.0f / EIG_H);
  float lam = 1.0f - minre;
  wsf[OFF_SC + 2] = lam;
  wsf[OFF_SC + 3] = 2.0f / lam - 1.0f;
  wsf[OFF_SC + 4] = 2.0f / lam;
}

__global__ __launch_bounds__(64) void k_colsum(const float* __restrict__ W,
                                               float* __restrict__ wsf) {
  const int m = blockIdx.x * 64 + threadIdx.x;
  float s1 = 0.f, s2 = 0.f;
  for (int n = 0; n < 512; ++n) {
    float w = W[n * 512 + m];
    s1 += w; s2 += w * w;
  }
  float wmm = W[m * 512 + m];
  float a = wsf[OFF_SC + 3], c = wsf[OFF_SC + 4];
  wsf[OFF_CS1 + m] = a - c * s1;
  wsf[OFF_CS2 + m] = 2.0f * (c * c * s2 + a * a - 2.0f * a * c * wmm) - 1.0f;
}

__global__ __launch_bounds__(256) void k_gemm_wx(
    const float* __restrict__ A, const float* __restrict__ Bm,
    float* __restrict__ C) {
  __shared__ float As[32][33], Bs[32][33];
  const int tx = threadIdx.x & 31, ty = threadIdx.x >> 5;
  const int rb = blockIdx.y * 32, cb = blockIdx.x * 32;
  float acc[4] = {0.f, 0.f, 0.f, 0.f};
  for (int kk = 0; kk < 512; kk += 32) {
    for (int idx = threadIdx.x; idx < 1024; idx += 256) {
      int r = idx >> 5, c = idx & 31;
      As[r][c] = A[(rb + r) * 512 + kk + c];
      Bs[r][c] = Bm[(kk + r) * 512 + cb + c];
    }
    __syncthreads();
    for (int k2 = 0; k2 < 32; ++k2) {
      float bvv = Bs[k2][tx];
      #pragma unroll
      for (int i = 0; i < 4; ++i) acc[i] += As[ty + 8 * i][k2] * bvv;
    }
    __syncthreads();
  }
  #pragma unroll
  for (int i = 0; i < 4; ++i)
    C[(rb + ty + 8 * i) * 512 + cb + tx] = acc[i];
}

__global__ __launch_bounds__(256) void k_gemm_yz(
    const float* __restrict__ X, const float* __restrict__ WX,
    const float* __restrict__ W, const float* __restrict__ sc,
    float* __restrict__ y1, float* __restrict__ y2,
    float* __restrict__ z1, float* __restrict__ z2) {
  __shared__ float Xs[32][33], Ms[32][33], C1s[32][33], C2s[32][33];
  const int tx = threadIdx.x & 31, ty = threadIdx.x >> 5;
  const int rb = blockIdx.y * 32, cb = blockIdx.x * 32;
  const float a = sc[3], c = sc[4];
  float ay1[4] = {0,0,0,0}, ay2[4] = {0,0,0,0}, az1[4] = {0,0,0,0}, az2[4] = {0,0,0,0};
  for (int kk = 0; kk < 512; kk += 32) {
    for (int idx = threadIdx.x; idx < 1024; idx += 256) {
      int r = idx >> 5, cc = idx & 31;
      Xs[r][cc] = X[(rb + r) * 512 + kk + cc];
      Ms[r][cc] = WX[(rb + r) * 512 + kk + cc];
      float w = W[(kk + r) * 512 + cb + cc];
      float dl = ((kk + r) == (cb + cc)) ? 1.0f : 0.0f;
      float c1 = a * dl - c * w;
      C1s[r][cc] = c1;
      C2s[r][cc] = 2.0f * c1 * c1 - dl;
    }
    __syncthreads();
    for (int k2 = 0; k2 < 32; ++k2) {
      float b1 = C1s[k2][tx], b2 = C2s[k2][tx];
      #pragma unroll
      for (int i = 0; i < 4; ++i) {
        float xv = Xs[ty + 8 * i][k2];
        float wv = Ms[ty + 8 * i][k2];
        ay1[i] += xv * b1; ay2[i] += xv * b2;
        az1[i] += wv * b1; az2[i] += wv * b2;
      }
    }
    __syncthreads();
  }
  #pragma unroll
  for (int i = 0; i < 4; ++i) {
    int off = (rb + ty + 8 * i) * 512 + cb + tx;
    y1[off] = ay1[i]; y2[off] = ay2[i];
    z1[off] = az1[i]; z2[off] = az2[i];
  }
}

// ---------------------------------------------------------------------------
// temporal branch v5 (k_temporal3): 8 seqs/block, thread-per-row, fp32.
//  - HSTR=66 -> 8B-aligned rows -> float2 LDS ops everywhere (2-way bank = free)
//  - decomp as per-column sliding window (512 col tasks over 256 threads):
//    1600 reads/thread -> 48 r+w per task
//  - LDS aux union (corr/wsm/dly | cmean | pr) -> 52736 B/block -> 3 blocks/CU
// ---------------------------------------------------------------------------
#define HSTR 66
#define HSTR2 33

__device__ __forceinline__ void decomp_cols(float* __restrict__ hl, int t) {
  #pragma unroll
  for (int task = 0; task < 2; ++task) {
    int id = task * 256 + t;
    int sq = id >> 6, e = id & 63;
    int base = sq * 24 * HSTR + e;
    float h24[24];
    #pragma unroll
    for (int ll = 0; ll < 24; ++ll) h24[ll] = hl[base + ll * HSTR];
    float W = 13.0f * h24[0];
    #pragma unroll
    for (int j = 1; j <= 12; ++j) W += h24[j];
    #pragma unroll
    for (int ll = 0; ll < 24; ++ll) {
      hl[base + ll * HSTR] = h24[ll] - W * (1.0f / 25.0f);
      int jp = (ll + 13 > 23) ? 23 : ll + 13;
      int jm = (ll - 12 < 0) ? 0 : ll - 12;
      W += h24[jp] - h24[jm];
    }
  }
}

__global__ __launch_bounds__(256, 3) void k_temporal3(
    const float* __restrict__ x, const float* __restrict__ pe,
    const float* __restrict__ Mw, const float* __restrict__ PTw,
    const float* __restrict__ C1T, const float* __restrict__ C2T,
    const float* __restrict__ bvo,
    const float* __restrict__ c1b, const float* __restrict__ c2b,
    const float* __restrict__ ng, const float* __restrict__ nbv,
    const float* __restrict__ decw, const float* __restrict__ decb,
    float* __restrict__ trelu) {
  __shared__ float hl[8 * 24 * HSTR];   // 50688 B
  __shared__ float aux[512];            // 2048 B (union: corr|wsm|dly / cmean / pr)
  float* corr_s = aux;                  // 192
  float* wsm_s  = aux + 192;            // 24
  int*   dly_s  = (int*)(aux + 216);    // 24
  float* cmean_s = aux;                 // 512 (post-loop, corr/wsm/dly dead)
  float* pr_s   = aux;                  // 192 (post-cmean, barrier-sequenced)

  const int t = threadIdx.x;
  const int s0 = blockIdx.x * 8;
  const bool active = t < 192;
  const int r = t;
  const int seq = r / 24;
  const int l = r - seq * 24;
  const int gseq = s0 + seq;
  const int b = gseq >> 9, n = gseq & 511;
  float2* hl2 = (float2*)hl;
  const int row2 = r * HSTR2;

  // ---- init h = x + pe ----
  if (active) {
    float xv = x[(b * 24 + l) * 512 + n];
    const float2* per = (const float2*)(pe + l * 64);
    #pragma unroll
    for (int c = 0; c < 32; ++c) {
      float2 pv = per[c];
      hl2[row2 + c] = make_float2(xv + pv.x, xv + pv.y);
    }
  }
  __syncthreads();

  for (int layer = 0; layer < 2; ++layer) {
    if (t < 192) corr_s[t] = 0.f;
    __syncthreads();
    // ---- u = M^T h (own row), then corr partials (float2 reads) ----
    if (active) {
      float u[64];
      #pragma unroll
      for (int e = 0; e < 64; ++e) u[e] = 0.f;
      for (int dd = 0; dd < 32; ++dd) {
        float2 hv = hl2[row2 + dd];
        const float* M0 = Mw + (2 * dd) * 64;
        const float* M1 = M0 + 64;
        #pragma unroll
        for (int e = 0; e < 64; ++e) u[e] += hv.x * M0[e] + hv.y * M1[e];
      }
      for (int tau = 0; tau < 24; ++tau) {
        int l2v = l - tau; if (l2v < 0) l2v += 24;
        int bb2 = (seq * 24 + l2v) * HSTR2;
        float acc = 0.f;
        #pragma unroll
        for (int dd = 0; dd < 32; ++dd) {
          float2 h2 = hl2[bb2 + dd];
          acc += u[2 * dd] * h2.x + u[2 * dd + 1] * h2.y;
        }
        atomicAdd(&corr_s[seq * 24 + tau], acc * (1.0f / 64.0f));
      }
    }
    __syncthreads();
    // ---- top-3 + softmax (per seq) ----
    if (t < 8) {
      const float* cr = corr_s + t * 24;
      int i0 = 0, i1 = 0, i2 = 0;
      float v0 = -3.4e38f, v1 = -3.4e38f, v2 = -3.4e38f;
      for (int j = 0; j < 24; ++j) { float v = cr[j]; if (v > v0) { v0 = v; i0 = j; } }
      for (int j = 0; j < 24; ++j) { if (j == i0) continue; float v = cr[j]; if (v > v1) { v1 = v; i1 = j; } }
      for (int j = 0; j < 24; ++j) { if (j == i0 || j == i1) continue; float v = cr[j]; if (v > v2) { v2 = v; i2 = j; } }
      float e1 = expf(v1 - v0), e2 = expf(v2 - v0);
      float inv = 1.0f / (1.0f + e1 + e2);
      wsm_s[t * 3] = inv; wsm_s[t * 3 + 1] = e1 * inv; wsm_s[t * 3 + 2] = e2 * inv;
      dly_s[t * 3] = i0; dly_s[t * 3 + 1] = i1; dly_s[t * 3 + 2] = i2;
    }
    __syncthreads();
    // ---- fused delay-agg + P matvec (float2 reads) ----
    {
      float acc[64];
      #pragma unroll
      for (int e = 0; e < 64; ++e) acc[e] = 0.f;
      if (active) {
        float w0 = wsm_s[seq * 3], w1 = wsm_s[seq * 3 + 1], w2 = wsm_s[seq * 3 + 2];
        int d0 = dly_s[seq * 3], d1 = dly_s[seq * 3 + 1], d2 = dly_s[seq * 3 + 2];
        int l0 = l + d0; if (l0 >= 24) l0 -= 24;
        int l1 = l + d1; if (l1 >= 24) l1 -= 24;
        int l2 = l + d2; if (l2 >= 24) l2 -= 24;
        int b0 = (seq * 24 + l0) * HSTR2, b1 = (seq * 24 + l1) * HSTR2, b2 = (seq * 24 + l2) * HSTR2;
        for (int dd = 0; dd < 32; ++dd) {
          float2 a0 = hl2[b0 + dd], a1 = hl2[b1 + dd], av2 = hl2[b2 + dd];
          float gx = w0 * a0.x + w1 * a1.x + w2 * av2.x;
          float gy = w0 * a0.y + w1 * a1.y + w2 * av2.y;
          const float* P0 = PTw + (2 * dd) * 64;
          const float* P1 = P0 + 64;
          #pragma unroll
          for (int e = 0; e < 64; ++e) acc[e] += gx * P0[e] + gy * P1[e];
        }
      }
      __syncthreads();   // all hl reads complete before writes
      if (active) {
        #pragma unroll
        for (int j = 0; j < 32; ++j) {
          float2 cur = hl2[row2 + j];
          cur.x += acc[2 * j] + bvo[2 * j];
          cur.y += acc[2 * j + 1] + bvo[2 * j + 1];
          hl2[row2 + j] = cur;
        }
      }
    }
    __syncthreads();
    decomp_cols(hl, t);
    __syncthreads();
    // ---- fused FF: conv1(relu) -> conv2, f-chunked by 16, float2 row reads ----
    {
      float a2[64];
      #pragma unroll
      for (int e = 0; e < 64; ++e) a2[e] = 0.f;
      if (active) {
        for (int fc = 0; fc < 16; ++fc) {
          float y16[16];
          #pragma unroll
          for (int f = 0; f < 16; ++f) y16[f] = 0.f;
          for (int dd = 0; dd < 32; ++dd) {
            float2 hv = hl2[row2 + dd];
            const float* c1a = C1T + (2 * dd) * 256 + fc * 16;
            const float* c1bp = c1a + 256;
            #pragma unroll
            for (int f = 0; f < 16; ++f) y16[f] += hv.x * c1a[f] + hv.y * c1bp[f];
          }
          #pragma unroll
          for (int f = 0; f < 16; ++f)
            y16[f] = fmaxf(y16[f] + c1b[fc * 16 + f], 0.0f);
          #pragma unroll
          for (int f = 0; f < 16; ++f) {
            float yf = y16[f];
            const float* r2 = C2T + (fc * 16 + f) * 64;
            #pragma unroll
            for (int e = 0; e < 64; ++e) a2[e] += yf * r2[e];
          }
        }
        #pragma unroll
        for (int j = 0; j < 32; ++j) {
          float2 cur = hl2[row2 + j];
          cur.x += a2[2 * j] + c2b[2 * j];
          cur.y += a2[2 * j + 1] + c2b[2 * j + 1];
          hl2[row2 + j] = cur;
        }
      }
    }
    __syncthreads();
    decomp_cols(hl, t);
    __syncthreads();
  }

  // ---- LayerNorm over D (float2, 3 passes) ----
  if (active) {
    float mu = 0.f;
    #pragma unroll
    for (int dd = 0; dd < 32; ++dd) { float2 v = hl2[row2 + dd]; mu += v.x + v.y; }
    mu *= (1.0f / 64.0f);
    float vs = 0.f;
    #pragma unroll
    for (int dd = 0; dd < 32; ++dd) {
      float2 v = hl2[row2 + dd];
      float dx = v.x - mu, dy = v.y - mu;
      vs += dx * dx + dy * dy;
    }
    float rs = rsqrtf(vs * (1.0f / 64.0f) + 1e-5f);
    #pragma unroll
    for (int dd = 0; dd < 32; ++dd) {
      float2 v = hl2[row2 + dd];
      v.x = (v.x - mu) * rs * ng[2 * dd] + nbv[2 * dd];
      v.y = (v.y - mu) * rs * ng[2 * dd + 1] + nbv[2 * dd + 1];
      hl2[row2 + dd] = v;
    }
  }
  __syncthreads();
  // ---- my_Layernorm: column means over L (into aux as cmean) ----
  #pragma unroll
  for (int pass = 0; pass < 2; ++pass) {
    int idx = pass * 256 + t;
    int sq2 = idx >> 6, e2 = idx & 63;
    float s = 0.f;
    for (int ll = 0; ll < 24; ++ll) s += hl[(sq2 * 24 + ll) * HSTR + e2];
    cmean_s[idx] = s * (1.0f / 24.0f);
  }
  __syncthreads();
  if (active) {
    #pragma unroll
    for (int j = 0; j < 32; ++j) {
      float2 v = hl2[row2 + j];
      v.x -= cmean_s[seq * 64 + 2 * j];
      v.y -= cmean_s[seq * 64 + 2 * j + 1];
      hl2[row2 + j] = v;
    }
  }
  __syncthreads();
  // ---- dec head (float2) ----
  if (active) {
    int g = t >> 3;            // 0..23
    int u = g >> 1, half = g & 1;
    int sq = t & 7;
    const float2* dwp2 = (const float2*)(decw + u * 1536 + half * 768);
    int hb2 = (sq * 24 + half * 12) * HSTR2;
    float part = 0.f;
    for (int j = 0; j < 384; ++j) {
      int lr = j >> 5, dd = j & 31;
      float2 hv = hl2[hb2 + lr * HSTR2 + dd];
      float2 wv = dwp2[j];
      part += hv.x * wv.x + hv.y * wv.y;
    }
    pr_s[t] = part;
  }
  __syncthreads();
  if (t < 96) {
    int u = t >> 3, sq = t & 7;
    float v = pr_s[(u * 2) * 8 + sq] + pr_s[(u * 2 + 1) * 8 + sq] + decb[u];
    trelu[(size_t)(s0 + sq) * 12 + u] = fmaxf(v, 0.0f);
  }
}

// ---------------------------------------------------------------------------
// final combine
// ---------------------------------------------------------------------------
__global__ __launch_bounds__(64) void k_final(
    const float* __restrict__ x, const float* __restrict__ wx,
    const float* __restrict__ y1, const float* __restrict__ y2,
    const float* __restrict__ z1, const float* __restrict__ z2,
    const float* __restrict__ cs1, const float* __restrict__ cs2,
    const float* __restrict__ trelu,
    const float* __restrict__ alpha, const float* __restrict__ beta,
    const float* __restrict__ theta,
    const float* __restrict__ slinw, const float* __restrict__ slinb,
    const float* __restrict__ tlinw, const float* __restrict__ tlinb,
    float* __restrict__ out) {
  __shared__ float ly0[24], ly1[24], ly2[24], lz0[24], lz1[24], lz2[24];
  __shared__ float ltr[12], lsw[288];
  const int blk = blockIdx.x;
  const int b = blk >> 9, m = blk & 511;
  const int t = threadIdx.x;
  if (t < 24) {
    int row = (b * 24 + t) * 512 + m;
    ly0[t] = x[row];  ly1[t] = y1[row]; ly2[t] = y2[row];
    lz0[t] = wx[row]; lz1[t] = z1[row]; lz2[t] = z2[row];
  }
  if (t >= 48 && t < 60) ltr[t - 48] = trelu[(b * 512 + m) * 12 + (t - 48)];
  for (int i = t; i < 288; i += 64) lsw[i] = slinw[i];
  __syncthreads();
  const int o = t;
  const float at = alpha[0] + alpha[1] * cs1[m] + alpha[2] * cs2[m];
  const float b0 = beta[o], b1 = beta[64 + o], b2 = beta[128 + o];
  const float t0 = theta[o], t1 = theta[64 + o], t2 = theta[128 + o];
  float so[12];
  #pragma unroll
  for (int u = 0; u < 12; ++u) so[u] = 0.f;
  for (int tt = 0; tt < 24; ++tt) {
    float v = at + b0 * ly0[tt] + b1 * ly1[tt] + b2 * ly2[tt]
                 + t0 * lz0[tt] + t1 * lz1[tt] + t2 * lz2[tt];
    v = fmaxf(v, 0.0f);
    #pragma unroll
    for (int u = 0; u < 12; ++u) so[u] += lsw[u * 24 + tt] * v;
  }
  const float tw = tlinw[o], tb = tlinb[o];
  #pragma unroll
  for (int u = 0; u < 12; ++u) {
    float sval = so[u] + slinb[u];
    float tval = tw * ltr[u] + tb;
    float rr = fmaxf(sval * tval, 0.0f);
    out[(((size_t)b * 12 + u) * 512 + m) * 64 + o] = rr;
  }
}

// ===========================================================================
extern "C" void kernel_launch(void* const* d_in, const int* in_sizes, int n_in,
                              void* d_out, int out_size, void* d_ws, size_t ws_size,
                              hipStream_t stream) {
  (void)in_sizes; (void)n_in; (void)out_size; (void)ws_size;
  const float* s_w    = (const float*)d_in[0];
  const float* x      = (const float*)d_in[1];
  const float* swnn_w = (const float*)d_in[2];
  const float* swnn_b = (const float*)d_in[3];
  const float* alpha  = (const float*)d_in[4];
  const float* beta   = (const float*)d_in[5];
  const float* theta  = (const float*)d_in[6];
  const float* wq = (const float*)d_in[7];  const float* bq = (const float*)d_in[8];
  const float* wk = (const float*)d_in[9];  const float* bk = (const float*)d_in[10];
  const float* wv = (const float*)d_in[11]; const float* bv = (const float*)d_in[12];
  const float* wo = (const float*)d_in[13]; const float* bo = (const float*)d_in[14];
  const float* c1w = (const float*)d_in[15]; const float* c1b = (const float*)d_in[16];
  const float* c2w = (const float*)d_in[17]; const float* c2b = (const float*)d_in[18];
  const float* ng  = (const float*)d_in[19]; const float* nb  = (const float*)d_in[20];
  const float* decw = (const float*)d_in[21]; const float* decb = (const float*)d_in[22];
  const float* slinw = (const float*)d_in[23]; const float* slinb = (const float*)d_in[24];
  const float* tlinw = (const float*)d_in[25]; const float* tlinb = (const float*)d_in[26];
  (void)bq; (void)bk;

  float* wsf = (float*)d_ws;
  float* out = (float*)d_out;

  float* Wm = wsf + OFF_W;
  float* Sa = wsf + OFF_SA;
  float* Sb = wsf + OFF_SB;
  unsigned int* mbits = (unsigned int*)(wsf + OFF_SC) + 8;
  const float* scal = wsf + OFF_SC;

  k_prep<<<1, 256, 0, stream>>>(wsf);
  k_wprep<<<6, 256, 0, stream>>>(wq, wk, wv, wo, bv, bo, c1w, c2w, wsf);
  k_gemm_logits<<<dim3(16, 16), 256, 0, stream>>>(s_w, swnn_w, swnn_b, Wm);
  k_softmax_rows<<<512, 64, 0, stream>>>(Wm);

  // temporal branch
  k_temporal3<<<2048, 256, 0, stream>>>(x, wsf + OFF_PE, wsf + OFF_M, wsf + OFF_PT,
                                        wsf + OFF_C1T, wsf + OFF_C2T, wsf + OFF_BVO,
                                        c1b, c2b, ng, nb, decw, decb, wsf + OFF_TR);

  // eigen: scaling-squaring + power iteration
  k_init_S<<<1024, 256, 0, stream>>>(wsf);
  float* cur = Sa;
  float* nxt = Sb;
  for (int j = 0; j < EIG_K; ++j) {
    k_gemm_square<<<dim3(16, 16), 256, 0, stream>>>(cur, nxt, scal, mbits);
    k_bookkeep<<<1, 1, 0, stream>>>(wsf);
    float* tmp = cur; cur = nxt; nxt = tmp;
  }
  float* va = wsf + OFF_V0;
  float* vb = wsf + OFF_V1;
  for (int p = 0; p < MV_STEPS; ++p) {
    k_matvec<<<8, 64, 0, stream>>>(cur, va, vb, wsf, p);
    float* tmp = va; va = vb; vb = tmp;
  }
  k_lamfin<<<1, 1, 0, stream>>>(wsf);

  // spatial branch
  k_colsum<<<8, 64, 0, stream>>>(Wm, wsf);
  k_gemm_wx<<<dim3(16, 24), 256, 0, stream>>>(x, Wm, wsf + OFF_WX);
  k_gemm_yz<<<dim3(16, 24), 256, 0, stream>>>(x, wsf + OFF_WX, Wm, scal,
                                              wsf + OFF_Y1, wsf + OFF_Y2,
                                              wsf + OFF_Z1, wsf + OFF_Z2);
  k_final<<<16384, 64, 0, stream>>>(x, wsf + OFF_WX, wsf + OFF_Y1, wsf + OFF_Y2,
                                    wsf + OFF_Z1, wsf + OFF_Z2,
                                    wsf + OFF_CS1, wsf + OFF_CS2, wsf + OFF_TR,
                                    alpha, beta, theta, slinw, slinb,
                                    tlinw, tlinb, out);
}